// Round 6
// baseline (635.967 us; speedup 1.0000x reference)
//
#include <hip/hip_runtime.h>

#define NB 16
#define NA 261888
#define PRE 6000
#define POST 1000
#define CAP 8192
#define NCH 24          // mask chunks of 8 words (256 cols) each
#define MROWS 6016      // mask rows allocated per batch
#define BOXSTRIDE 6144  // box slots allocated per batch
#define THRF 0.972f     // fixed fast-path threshold; E[cnt]=7333, 15.8 sigma > PRE, 10.2 sigma < CAP
// Exact NMS predicate: RN32(inter/denom) > 0.7f  <=>  inter >= MBOUND * denom
// MBOUND = midpoint(0.7f, nextafterf(0.7f,inf)) = 0x1.666667p-1 (bit24 set).
// 25-bit mantissa x 24-bit denom -> f64 product exact; tie q==M rounds to even
// (0x1.666668p-1) > 0.7f so ">=" is the correct inclusive test.
#define MBOUND 0x1.666667p-1

typedef unsigned int u32;
typedef unsigned long long u64;

__device__ inline float box_area(float4 v) {
    return __fmul_rn(__fadd_rn(__fsub_rn(v.z, v.x), 1.0f),
                     __fadd_rn(__fsub_rn(v.w, v.y), 1.0f));
}

// ---------------- anchors (match numpy float64 -> float32 exactly) -------------
__device__ inline void anchor_at(int idx, float& a0, float& a1, float& a2, float& a3) {
    int base, fw, stride, scale;
    if (idx < 196608)      { base = 0;      fw = 256; stride = 4;  scale = 4; }
    else if (idx < 245760) { base = 196608; fw = 128; stride = 8;  scale = 8; }
    else if (idx < 258048) { base = 245760; fw = 64;  stride = 16; scale = 16; }
    else if (idx < 261120) { base = 258048; fw = 32;  stride = 32; scale = 32; }
    else                   { base = 261120; fw = 16;  stride = 64; scale = 64; }
    int rel  = idx - base;
    int ri   = rel % 3;
    int cell = rel / 3;
    int col  = cell & (fw - 1);
    int row  = cell / fw;
    double cx = (col + 0.5) * (double)stride;
    double cy = (row + 0.5) * (double)stride;
    double sz = (double)scale * 8.0;
    double sq = (ri == 0) ? 0.7071067811865476 : ((ri == 1) ? 1.0 : 1.4142135623730951);
    double wsd = sz * sq;
    double hsd = sz / sq;
    a0 = (float)(cx - 0.5 * wsd);
    a1 = (float)(cy - 0.5 * hsd);
    a2 = (float)(cx + 0.5 * wsd);
    a3 = (float)(cy + 0.5 * hsd);
}

// ---------------- fast path: fixed-threshold compact, block-aggregated ---------
__global__ void compact_fixed(const float* __restrict__ probs, u32* __restrict__ cntp,
                              u64* __restrict__ cand) {
    __shared__ u32 lcnt;
    __shared__ u32 lbase;
    int tid = threadIdx.x;
    int a = blockIdx.x * 256 + tid;          // NA == 1023*256, no tail
    int b = blockIdx.y;
    if (tid == 0) lcnt = 0;
    __syncthreads();
    float s = probs[((size_t)b * NA + a) * 2 + 1];
    u32 bits = __float_as_uint(s);
    int lpos = -1;
    if (s >= THRF) lpos = (int)atomicAdd(&lcnt, 1u);
    __syncthreads();
    if (tid == 0) lbase = lcnt ? atomicAdd(&cntp[b * 64], lcnt) : 0u;
    __syncthreads();
    if (lpos >= 0) {
        u32 pos = lbase + (u32)lpos;
        if (pos < CAP)
            cand[(size_t)b * CAP + pos] = ((u64)bits << 32) | (u32)(~(u32)a);
    }
}

// ---------------- validate fast path; set per-batch fallback flags -------------
__global__ void check_kernel(u32* __restrict__ cntp, u32* __restrict__ flag) {
    int t = threadIdx.x;
    if (t < NB) {
        u32 c = cntp[t * 64];
        u32 bad = (c < (u32)PRE || c > (u32)CAP) ? 1u : 0u;
        flag[t * 64] = bad;
        if (bad) cntp[t * 64] = 0;   // fallback compact restarts from 0
    }
}

// ---------------- gated fallback: zero hist ------------------------------------
__global__ void zero_hist(const u32* __restrict__ flag, u32* __restrict__ hist) {
    int b = blockIdx.y;
    if (flag[b * 64] == 0) return;
    int i = blockIdx.x * 256 + threadIdx.x;
    hist[(size_t)b * 65536 + i] = 0;
}

// ---------------- gated fallback: histogram of score bits (top 16) -------------
__global__ void hist_kernel(const u32* __restrict__ flag, const float* __restrict__ probs,
                            u32* __restrict__ hist) {
    int b = blockIdx.y;
    if (flag[b * 64] == 0) return;
    int a = blockIdx.x * 256 + threadIdx.x;
    float s = probs[((size_t)b * NA + a) * 2 + 1];
    u32 bits = __float_as_uint(s);
    atomicAdd(&hist[(size_t)b * 65536 + (bits >> 16)], 1u);
}

// ---------------- gated fallback: per-batch threshold --------------------------
__global__ __launch_bounds__(1024) void thresh_kernel(const u32* __restrict__ flag,
                                                      const u32* __restrict__ hist,
                                                      u32* __restrict__ thr) {
    int b = blockIdx.x;
    if (flag[b * 64] == 0) return;
    __shared__ u32 csum[1024];
    int t = threadIdx.x;
    const u32* h = hist + (size_t)b * 65536;
    u32 s = 0;
    for (int k = 0; k < 64; k++) s += h[t * 64 + k];
    csum[t] = s;
    __syncthreads();
    if (t == 0) {
        u32 cum = 0;
        int bucket = 0;
        for (int c = 1023; c >= 0; c--) {
            if (cum + csum[c] >= (u32)PRE) {
                u32 cum2 = cum;
                for (int k = 63; k >= 0; k--) {
                    cum2 += h[c * 64 + k];
                    if (cum2 >= (u32)PRE) { bucket = c * 64 + k; break; }
                }
                break;
            }
            cum += csum[c];
        }
        thr[b] = (u32)bucket << 16;
    }
}

// ---------------- gated fallback: compact with exact threshold -----------------
__global__ void compact2_kernel(const u32* __restrict__ flag, const float* __restrict__ probs,
                                const u32* __restrict__ thr, u32* __restrict__ cntp,
                                u64* __restrict__ cand) {
    int b = blockIdx.y;
    if (flag[b * 64] == 0) return;
    __shared__ u32 lcnt;
    __shared__ u32 lbase;
    int tid = threadIdx.x;
    int a = blockIdx.x * 256 + tid;
    if (tid == 0) lcnt = 0;
    __syncthreads();
    float s = probs[((size_t)b * NA + a) * 2 + 1];
    u32 bits = __float_as_uint(s);
    int lpos = -1;
    if (bits >= thr[b]) lpos = (int)atomicAdd(&lcnt, 1u);
    __syncthreads();
    if (tid == 0) lbase = lcnt ? atomicAdd(&cntp[b * 64], lcnt) : 0u;
    __syncthreads();
    if (lpos >= 0) {
        u32 pos = lbase + (u32)lpos;
        if (pos < CAP)
            cand[(size_t)b * CAP + pos] = ((u64)bits << 32) | (u32)(~(u32)a);
    }
}

// ---------------- per-batch bitonic sort of candidate keys ---------------------
__global__ __launch_bounds__(1024) void sort_kernel(u64* __restrict__ cand, const u32* __restrict__ cntp) {
    __shared__ u64 keys[CAP];
    int b = blockIdx.x, tid = threadIdx.x;
    int n = (int)min(cntp[b * 64], (u32)CAP);
    u64* cb = cand + (size_t)b * CAP;
    for (int i = tid; i < CAP; i += 1024) keys[i] = (i < n) ? cb[i] : 0ULL;
    __syncthreads();
    for (int k = 2; k <= CAP; k <<= 1) {
        for (int j = k >> 1; j > 0; j >>= 1) {
            for (int i = tid; i < CAP; i += 1024) {
                int ixj = i ^ j;
                if (ixj > i) {
                    u64 x = keys[i], y = keys[ixj];
                    bool desc = ((i & k) == 0);
                    if (desc ? (x < y) : (x > y)) { keys[i] = y; keys[ixj] = x; }
                }
            }
            __syncthreads();
        }
    }
    for (int i = tid; i < PRE; i += 1024) cb[i] = keys[i];
}

// ---------------- decode+clip top-PRE boxes; prefill output --------------------
__global__ void decode_kernel(const u64* __restrict__ cand, const float* __restrict__ deltas,
                              const float* __restrict__ img_info, float4* __restrict__ boxes,
                              float* __restrict__ out) {
    int s = blockIdx.x * 256 + threadIdx.x;
    int b = blockIdx.y;
    if (s < POST) {
        float* o = out + ((size_t)b * POST + s) * 5;
        o[0] = (float)b; o[1] = 0.f; o[2] = 0.f; o[3] = 0.f; o[4] = 0.f;
    }
    if (s >= BOXSTRIDE) return;
    if (s >= PRE) { boxes[(size_t)b * BOXSTRIDE + s] = make_float4(0.f, 0.f, 0.f, 0.f); return; }

    u64 key = cand[(size_t)b * CAP + s];
    int a = (int)(~(u32)key);
    float a0, a1, a2, a3;
    anchor_at(a, a0, a1, a2, a3);
    const float4 d4 = *(const float4*)(deltas + ((size_t)b * NA + a) * 4);
    float hmax = __fsub_rn(img_info[b * 3 + 0], 1.0f);
    float wmax = __fsub_rn(img_info[b * 3 + 1], 1.0f);
    float w  = __fadd_rn(__fsub_rn(a2, a0), 1.0f);
    float h  = __fadd_rn(__fsub_rn(a3, a1), 1.0f);
    float cx = __fadd_rn(a0, __fmul_rn(0.5f, w));
    float cy = __fadd_rn(a1, __fmul_rn(0.5f, h));
    float pcx = __fadd_rn(__fmul_rn(d4.x, w), cx);
    float pcy = __fadd_rn(__fmul_rn(d4.y, h), cy);
    float pw  = __fmul_rn((float)exp((double)d4.z), w);
    float ph  = __fmul_rn((float)exp((double)d4.w), h);
    float x1 = __fsub_rn(pcx, __fmul_rn(0.5f, pw));
    float y1 = __fsub_rn(pcy, __fmul_rn(0.5f, ph));
    float x2 = __fadd_rn(pcx, __fmul_rn(0.5f, pw));
    float y2 = __fadd_rn(pcy, __fmul_rn(0.5f, ph));
    x1 = fminf(fmaxf(x1, 0.f), wmax);
    x2 = fminf(fmaxf(x2, 0.f), wmax);
    y1 = fminf(fmaxf(y1, 0.f), hmax);
    y2 = fminf(fmaxf(y2, 0.f), hmax);
    boxes[(size_t)b * BOXSTRIDE + s] = make_float4(x1, y1, x2, y2);
}

// ---------------- IoU suppression bit-mask build (tile-pair blocks) ------------
// Chunk-major layout: maskC[b][chunk][row][8 words]. One block per upper-
// triangle 256x256 tile (300 per batch). Thread owns one row; accumulates 8
// words in registers; writes a dense 32B record (full-line coalesced writes).
__global__ __launch_bounds__(256) void mask_kernel(const float4* __restrict__ boxes,
                                                   u32* __restrict__ maskC) {
    __shared__ float4 cbox[256];
    __shared__ float  carea[256];
    int lin = blockIdx.x;          // 0..299 over pairs (rt, cc) with cc >= rt
    int b = blockIdx.y;
    int rt = 0, rem = lin;
    while (rem >= NCH - rt) { rem -= NCH - rt; ++rt; }
    int cc = rt + rem;
    int t = threadIdx.x;
    const float4* bb = boxes + (size_t)b * BOXSTRIDE;

    float4 cv = bb[cc * 256 + t];
    cbox[t] = cv;
    carea[t] = box_area(cv);
    __syncthreads();

    int row = rt * 256 + t;
    float4 rb = bb[row];
    float  ra = box_area(rb);
    const double md = MBOUND;

    u32 acc[8];
    #pragma unroll
    for (int g = 0; g < 8; ++g) {
        u32 a = 0;
        #pragma unroll
        for (int k = 0; k < 32; ++k) {
            float4 cb = cbox[g * 32 + k];     // uniform LDS broadcast
            float  ca = carea[g * 32 + k];
            float xx1 = fmaxf(cb.x, rb.x);
            float yy1 = fmaxf(cb.y, rb.y);
            float xx2 = fminf(cb.z, rb.z);
            float yy2 = fminf(cb.w, rb.w);
            float iw = fmaxf(__fadd_rn(__fsub_rn(xx2, xx1), 1.0f), 0.f);
            float ih = fmaxf(__fadd_rn(__fsub_rn(yy2, yy1), 1.0f), 0.f);
            float inter = __fmul_rn(iw, ih);
            float denom = __fsub_rn(__fadd_rn(ca, ra), inter);
            u32 s = ((double)inter >= md * (double)denom) ? 1u : 0u;
            a |= s << k;
        }
        acc[g] = a;
    }
    if (row < MROWS) {
        uint4* rec = (uint4*)(maskC + (((size_t)b * NCH + cc) * MROWS + row) * 8);
        rec[0] = make_uint4(acc[0], acc[1], acc[2], acc[3]);
        rec[1] = make_uint4(acc[4], acc[5], acc[6], acc[7]);
    }
}

// ---------------- streaming greedy NMS scan (one wave per batch) ---------------
// Chunk-major reads: lane l covers words 4l..4l+3 = chunk l>>1, half (l&1).
// 32-deep prefetch ring, triangle-predicated loads; scalar aliveness via
// readlane; suppression gated per-word by (wb+k >= w).
__global__ __launch_bounds__(64) void scan_kernel(const u32* __restrict__ maskC,
                                                  const float4* __restrict__ boxes,
                                                  float* __restrict__ out) {
    __shared__ int keepIdx[POST];
    int b = blockIdx.x, l = threadIdx.x;
    int wb = 4 * l;
    u32 aw0 = (wb     < 187) ? 0xFFFFFFFFu : ((wb     == 187) ? 0xFFFFu : 0u);
    u32 aw1 = (wb + 1 < 187) ? 0xFFFFFFFFu : ((wb + 1 == 187) ? 0xFFFFu : 0u);
    u32 aw2 = (wb + 2 < 187) ? 0xFFFFFFFFu : ((wb + 2 == 187) ? 0xFFFFu : 0u);
    u32 aw3 = (wb + 3 < 187) ? 0xFFFFFFFFu : ((wb + 3 == 187) ? 0xFFFFu : 0u);
    int cl = l >> 1; if (cl > NCH - 1) cl = NCH - 1;
    bool laneLive = (wb <= 187);
    const u32* base = maskC + ((size_t)b * NCH + cl) * MROWS * 8 + (l & 1) * 4;

    uint4 pf[32];
    #pragma unroll
    for (int u = 0; u < 32; ++u)
        if (laneLive) pf[u] = *(const uint4*)(base + (size_t)u * 8);

    int kept = 0;
    for (int ib = 0; ib < PRE; ib += 32) {
        int w = ib >> 5;
        int ol = w >> 2;
        int q = w & 3;
        u32 awsel = (q == 0) ? aw0 : (q == 1) ? aw1 : (q == 2) ? aw2 : aw3;
        u32 blockAlive = __builtin_amdgcn_readlane(awsel, ol);
        #pragma unroll
        for (int u = 0; u < 32; ++u) {
            int i = ib + u;
            uint4 r = pf[u];
            int pr = i + 32; if (pr > MROWS - 1) pr = MROWS - 1;
            if (laneLive && (wb + 3 >= (pr >> 5)))
                pf[u] = *(const uint4*)(base + (size_t)pr * 8);
            if (blockAlive & (1u << u)) {
                if (l == 0) keepIdx[kept] = i;
                ++kept;
                if (kept == POST) goto scan_done;
                aw0 &= ~((wb     >= w) ? r.x : 0u);
                aw1 &= ~((wb + 1 >= w) ? r.y : 0u);
                aw2 &= ~((wb + 2 >= w) ? r.z : 0u);
                aw3 &= ~((wb + 3 >= w) ? r.w : 0u);
                u32 as2 = (q == 0) ? aw0 : (q == 1) ? aw1 : (q == 2) ? aw2 : aw3;
                blockAlive = __builtin_amdgcn_readlane(as2, ol);
            }
        }
    }
scan_done:
    __syncthreads();
    for (int s = l; s < kept; s += 64) {
        int j = keepIdx[s];
        float4 bx = boxes[(size_t)b * BOXSTRIDE + j];
        float* o = out + ((size_t)b * POST + s) * 5;
        o[0] = (float)b; o[1] = bx.x; o[2] = bx.y; o[3] = bx.z; o[4] = bx.w;
    }
}

// ---------------- fallback: monolithic sort+decode+NMS (small ws) --------------
__global__ __launch_bounds__(1024) void final_kernel(const u64* __restrict__ cand, const u32* __restrict__ cntp,
                             const float* __restrict__ deltas, const float* __restrict__ img_info,
                             float* __restrict__ out) {
    __shared__ union {
        u64 keys[CAP];
        struct {
            float boxes[PRE][4];
            float areas[PRE];
            u32   alive[192];
        } n;
    } sh;
    __shared__ int s_next;

    int b = blockIdx.x;
    int tid = threadIdx.x;

    for (int s = tid; s < POST; s += 1024) {
        float* o = out + ((size_t)b * POST + s) * 5;
        o[0] = (float)b; o[1] = 0.f; o[2] = 0.f; o[3] = 0.f; o[4] = 0.f;
    }

    int n = (int)min(cntp[b * 64], (u32)CAP);
    for (int i = tid; i < CAP; i += 1024)
        sh.keys[i] = (i < n) ? cand[(size_t)b * CAP + i] : 0ULL;
    __syncthreads();

    for (int k = 2; k <= CAP; k <<= 1) {
        for (int j = k >> 1; j > 0; j >>= 1) {
            for (int i = tid; i < CAP; i += 1024) {
                int ixj = i ^ j;
                if (ixj > i) {
                    u64 x = sh.keys[i], y = sh.keys[ixj];
                    bool desc = ((i & k) == 0);
                    if (desc ? (x < y) : (x > y)) { sh.keys[i] = y; sh.keys[ixj] = x; }
                }
            }
            __syncthreads();
        }
    }

    u32 myIdx[6];
    #pragma unroll
    for (int r = 0; r < 6; r++) {
        int i = tid + r * 1024;
        if (i < PRE) myIdx[r] = ~(u32)(sh.keys[i]);
    }
    __syncthreads();

    float hmax = __fsub_rn(img_info[b * 3 + 0], 1.0f);
    float wmax = __fsub_rn(img_info[b * 3 + 1], 1.0f);

    #pragma unroll
    for (int r = 0; r < 6; r++) {
        int i = tid + r * 1024;
        if (i < PRE) {
            int a = (int)myIdx[r];
            float a0, a1, a2, a3;
            anchor_at(a, a0, a1, a2, a3);
            const float4 d4 = *(const float4*)(deltas + ((size_t)b * NA + a) * 4);
            float w  = __fadd_rn(__fsub_rn(a2, a0), 1.0f);
            float h  = __fadd_rn(__fsub_rn(a3, a1), 1.0f);
            float cx = __fadd_rn(a0, __fmul_rn(0.5f, w));
            float cy = __fadd_rn(a1, __fmul_rn(0.5f, h));
            float pcx = __fadd_rn(__fmul_rn(d4.x, w), cx);
            float pcy = __fadd_rn(__fmul_rn(d4.y, h), cy);
            float pw  = __fmul_rn((float)exp((double)d4.z), w);
            float ph  = __fmul_rn((float)exp((double)d4.w), h);
            float x1 = __fsub_rn(pcx, __fmul_rn(0.5f, pw));
            float y1 = __fsub_rn(pcy, __fmul_rn(0.5f, ph));
            float x2 = __fadd_rn(pcx, __fmul_rn(0.5f, pw));
            float y2 = __fadd_rn(pcy, __fmul_rn(0.5f, ph));
            x1 = fminf(fmaxf(x1, 0.f), wmax);
            x2 = fminf(fmaxf(x2, 0.f), wmax);
            y1 = fminf(fmaxf(y1, 0.f), hmax);
            y2 = fminf(fmaxf(y2, 0.f), hmax);
            sh.n.boxes[i][0] = x1; sh.n.boxes[i][1] = y1;
            sh.n.boxes[i][2] = x2; sh.n.boxes[i][3] = y2;
            sh.n.areas[i] = __fmul_rn(__fadd_rn(__fsub_rn(x2, x1), 1.0f),
                                      __fadd_rn(__fsub_rn(y2, y1), 1.0f));
        }
    }

    for (int wdi = tid; wdi < 192; wdi += 1024) {
        u32 v = 0xFFFFFFFFu;
        if (wdi == 187) v = 0x0000FFFFu;
        if (wdi > 187)  v = 0u;
        sh.n.alive[wdi] = v;
    }
    __syncthreads();

    int kept = 0;
    int scanWord = 0;
    while (kept < POST) {
        if (tid == 0) {
            int found = -1;
            while (scanWord < 188) {
                u32 wv = sh.n.alive[scanWord];
                if (wv) { found = scanWord * 32 + (__ffs(wv) - 1); break; }
                scanWord++;
            }
            s_next = found;
        }
        __syncthreads();
        int i = s_next;
        if (i < 0) break;
        float bx1 = sh.n.boxes[i][0], by1 = sh.n.boxes[i][1];
        float bx2 = sh.n.boxes[i][2], by2 = sh.n.boxes[i][3];
        float bar = sh.n.areas[i];
        if (tid == 0) {
            float* o = out + ((size_t)b * POST + kept) * 5;
            o[1] = bx1; o[2] = by1; o[3] = bx2; o[4] = by2;
            atomicAnd(&sh.n.alive[i >> 5], ~(1u << (i & 31)));
        }
        for (int j = i + 1 + tid; j < PRE; j += 1024) {
            float x1 = sh.n.boxes[j][0], y1 = sh.n.boxes[j][1];
            float x2 = sh.n.boxes[j][2], y2 = sh.n.boxes[j][3];
            float xx1 = fmaxf(x1, bx1), yy1 = fmaxf(y1, by1);
            float xx2 = fminf(x2, bx2), yy2 = fminf(y2, by2);
            float iw = fmaxf(__fadd_rn(__fsub_rn(xx2, xx1), 1.0f), 0.f);
            float ih = fmaxf(__fadd_rn(__fsub_rn(yy2, yy1), 1.0f), 0.f);
            float inter = __fmul_rn(iw, ih);
            float denom = __fsub_rn(__fadd_rn(sh.n.areas[j], bar), inter);
            float iou = __fdiv_rn(inter, denom);
            if (iou > 0.7f) atomicAnd(&sh.n.alive[j >> 5], ~(1u << (j & 31)));
        }
        kept++;
        __syncthreads();
    }
}

// ---------------- launcher -----------------------------------------------------
extern "C" void kernel_launch(void* const* d_in, const int* in_sizes, int n_in,
                              void* d_out, int out_size, void* d_ws, size_t ws_size,
                              hipStream_t stream) {
    const float* probs    = (const float*)d_in[0];
    const float* deltas   = (const float*)d_in[1];
    const float* img_info = (const float*)d_in[2];
    float* out = (float*)d_out;

    char* ws = (char*)d_ws;
    size_t off = 0;
    u32* cntp = (u32*)(ws + off); off += (size_t)NB * 64 * sizeof(u32);      // 4 KiB, 256B-strided counters
    u32* flag = (u32*)(ws + off); off += (size_t)NB * 64 * sizeof(u32);      // 4 KiB
    u32* thr  = (u32*)(ws + off); off += 4096;                                // 16 u32 (padded)
    u32* hist = (u32*)(ws + off); off += (size_t)NB * 65536 * sizeof(u32);   // 4 MiB
    u64* cand = (u64*)(ws + off); off += (size_t)NB * CAP * sizeof(u64);     // 1 MiB
    float4* boxes = (float4*)(ws + off); off += (size_t)NB * BOXSTRIDE * sizeof(float4); // 1.5 MiB
    u32* maskC = (u32*)(ws + off); off += (size_t)NB * NCH * MROWS * 8 * sizeof(u32);    // 73.9 MiB
    bool bigws = (ws_size >= off);

    dim3 gA((NA + 255) / 256, NB);

    hipMemsetAsync(cntp, 0, (size_t)NB * 64 * sizeof(u32), stream);

    if (bigws) {
        compact_fixed<<<gA, 256, 0, stream>>>(probs, cntp, cand);
        check_kernel<<<1, 64, 0, stream>>>(cntp, flag);
        // gated exact fallback (no-ops when all flags clean)
        zero_hist<<<dim3(256, NB), 256, 0, stream>>>(flag, hist);
        hist_kernel<<<gA, 256, 0, stream>>>(flag, probs, hist);
        thresh_kernel<<<NB, 1024, 0, stream>>>(flag, hist, thr);
        compact2_kernel<<<gA, 256, 0, stream>>>(flag, probs, thr, cntp, cand);
        // main pipeline
        sort_kernel<<<NB, 1024, 0, stream>>>(cand, cntp);
        decode_kernel<<<dim3(BOXSTRIDE / 256, NB), 256, 0, stream>>>(cand, deltas, img_info, boxes, out);
        mask_kernel<<<dim3(300, NB), 256, 0, stream>>>(boxes, maskC);
        scan_kernel<<<NB, 64, 0, stream>>>(maskC, boxes, out);
    } else {
        // small-ws: force fallback flags on, run exact path + monolithic NMS
        hipMemsetAsync(flag, 1, (size_t)NB * 64 * sizeof(u32), stream);   // nonzero == run
        hipMemsetAsync(hist, 0, (size_t)NB * 65536 * sizeof(u32), stream);
        hist_kernel<<<gA, 256, 0, stream>>>(flag, probs, hist);
        thresh_kernel<<<NB, 1024, 0, stream>>>(flag, hist, thr);
        compact2_kernel<<<gA, 256, 0, stream>>>(flag, probs, thr, cntp, cand);
        final_kernel<<<NB, 1024, 0, stream>>>(cand, cntp, deltas, img_info, out);
    }
}

// Round 7
// 552.389 us; speedup vs baseline: 1.1513x; 1.1513x over previous
//
#include <hip/hip_runtime.h>

#define NB 16
#define NA 261888
#define PRE 6000
#define POST 1000
#define CAP 8192
#define SEG 256
#define NSEG ((PRE + SEG - 1) / SEG)   // 24
#define THRF 0.972f     // fixed fast-path threshold; E[cnt]=7333, 15.8 sigma > PRE, 10.2 sigma < CAP
// Exact NMS predicate: RN32(inter/denom) > 0.7f  <=>  inter >= MBOUND * denom
// MBOUND = midpoint(0.7f, nextafterf(0.7f,inf)) = 0x1.666667p-1 (bit24 set).
// 25-bit mantissa x 24-bit denom -> f64 product exact; tie q==M rounds to even
// (0x1.666668p-1) > 0.7f so ">=" is the correct inclusive test.
#define MBOUND 0x1.666667p-1

typedef unsigned int u32;
typedef unsigned long long u64;

__device__ inline float box_area(float4 v) {
    return __fmul_rn(__fadd_rn(__fsub_rn(v.z, v.x), 1.0f),
                     __fadd_rn(__fsub_rn(v.w, v.y), 1.0f));
}

__device__ inline bool iou_supp(float4 a, float aa, float4 c, float ca) {
    float xx1 = fmaxf(c.x, a.x);
    float yy1 = fmaxf(c.y, a.y);
    float xx2 = fminf(c.z, a.z);
    float yy2 = fminf(c.w, a.w);
    float iw = fmaxf(__fadd_rn(__fsub_rn(xx2, xx1), 1.0f), 0.f);
    float ih = fmaxf(__fadd_rn(__fsub_rn(yy2, yy1), 1.0f), 0.f);
    float inter = __fmul_rn(iw, ih);
    float denom = __fsub_rn(__fadd_rn(ca, aa), inter);
    return ((double)inter >= (double)MBOUND * (double)denom);
}

// ---------------- anchors (match numpy float64 -> float32 exactly) -------------
__device__ inline void anchor_at(int idx, float& a0, float& a1, float& a2, float& a3) {
    int base, fw, stride, scale;
    if (idx < 196608)      { base = 0;      fw = 256; stride = 4;  scale = 4; }
    else if (idx < 245760) { base = 196608; fw = 128; stride = 8;  scale = 8; }
    else if (idx < 258048) { base = 245760; fw = 64;  stride = 16; scale = 16; }
    else if (idx < 261120) { base = 258048; fw = 32;  stride = 32; scale = 32; }
    else                   { base = 261120; fw = 16;  stride = 64; scale = 64; }
    int rel  = idx - base;
    int ri   = rel % 3;
    int cell = rel / 3;
    int col  = cell & (fw - 1);
    int row  = cell / fw;
    double cx = (col + 0.5) * (double)stride;
    double cy = (row + 0.5) * (double)stride;
    double sz = (double)scale * 8.0;
    double sq = (ri == 0) ? 0.7071067811865476 : ((ri == 1) ? 1.0 : 1.4142135623730951);
    double wsd = sz * sq;
    double hsd = sz / sq;
    a0 = (float)(cx - 0.5 * wsd);
    a1 = (float)(cy - 0.5 * hsd);
    a2 = (float)(cx + 0.5 * wsd);
    a3 = (float)(cy + 0.5 * hsd);
}

__device__ inline float4 decode_box(u64 key, int b, const float* __restrict__ deltas,
                                    float hmax, float wmax) {
    int a = (int)(~(u32)key);
    float a0, a1, a2, a3;
    anchor_at(a, a0, a1, a2, a3);
    const float4 d4 = *(const float4*)(deltas + ((size_t)b * NA + a) * 4);
    float w  = __fadd_rn(__fsub_rn(a2, a0), 1.0f);
    float h  = __fadd_rn(__fsub_rn(a3, a1), 1.0f);
    float cx = __fadd_rn(a0, __fmul_rn(0.5f, w));
    float cy = __fadd_rn(a1, __fmul_rn(0.5f, h));
    float pcx = __fadd_rn(__fmul_rn(d4.x, w), cx);
    float pcy = __fadd_rn(__fmul_rn(d4.y, h), cy);
    float pw  = __fmul_rn((float)exp((double)d4.z), w);
    float ph  = __fmul_rn((float)exp((double)d4.w), h);
    float x1 = __fsub_rn(pcx, __fmul_rn(0.5f, pw));
    float y1 = __fsub_rn(pcy, __fmul_rn(0.5f, ph));
    float x2 = __fadd_rn(pcx, __fmul_rn(0.5f, pw));
    float y2 = __fadd_rn(pcy, __fmul_rn(0.5f, ph));
    x1 = fminf(fmaxf(x1, 0.f), wmax);
    x2 = fminf(fmaxf(x2, 0.f), wmax);
    y1 = fminf(fmaxf(y1, 0.f), hmax);
    y2 = fminf(fmaxf(y2, 0.f), hmax);
    return make_float4(x1, y1, x2, y2);
}

// ---------------- fast path: fixed-threshold compact, block-aggregated ---------
__global__ void compact_fixed(const float* __restrict__ probs, u32* __restrict__ cntp,
                              u64* __restrict__ cand) {
    __shared__ u32 lcnt;
    __shared__ u32 lbase;
    int tid = threadIdx.x;
    int a = blockIdx.x * 256 + tid;          // NA == 1023*256, no tail
    int b = blockIdx.y;
    if (tid == 0) lcnt = 0;
    __syncthreads();
    float s = probs[((size_t)b * NA + a) * 2 + 1];
    u32 bits = __float_as_uint(s);
    int lpos = -1;
    if (s >= THRF) lpos = (int)atomicAdd(&lcnt, 1u);
    __syncthreads();
    if (tid == 0) lbase = lcnt ? atomicAdd(&cntp[b * 64], lcnt) : 0u;
    __syncthreads();
    if (lpos >= 0) {
        u32 pos = lbase + (u32)lpos;
        if (pos < CAP)
            cand[(size_t)b * CAP + pos] = ((u64)bits << 32) | (u32)(~(u32)a);
    }
}

// ---------------- validate fast path; set per-batch fallback flags -------------
__global__ void check_kernel(u32* __restrict__ cntp, u32* __restrict__ flag) {
    int t = threadIdx.x;
    if (t < NB) {
        u32 c = cntp[t * 64];
        u32 bad = (c < (u32)PRE || c > (u32)CAP) ? 1u : 0u;
        flag[t * 64] = bad;
        if (bad) cntp[t * 64] = 0;   // fallback compact restarts from 0
    }
}

// ---------------- gated fallback: zero hist ------------------------------------
__global__ void zero_hist(const u32* __restrict__ flag, u32* __restrict__ hist) {
    int b = blockIdx.y;
    if (flag[b * 64] == 0) return;
    int i = blockIdx.x * 256 + threadIdx.x;
    hist[(size_t)b * 65536 + i] = 0;
}

// ---------------- gated fallback: histogram of score bits (top 16) -------------
__global__ void hist_kernel(const u32* __restrict__ flag, const float* __restrict__ probs,
                            u32* __restrict__ hist) {
    int b = blockIdx.y;
    if (flag[b * 64] == 0) return;
    int a = blockIdx.x * 256 + threadIdx.x;
    float s = probs[((size_t)b * NA + a) * 2 + 1];
    u32 bits = __float_as_uint(s);
    atomicAdd(&hist[(size_t)b * 65536 + (bits >> 16)], 1u);
}

// ---------------- gated fallback: per-batch threshold --------------------------
__global__ __launch_bounds__(1024) void thresh_kernel(const u32* __restrict__ flag,
                                                      const u32* __restrict__ hist,
                                                      u32* __restrict__ thr) {
    int b = blockIdx.x;
    if (flag[b * 64] == 0) return;
    __shared__ u32 csum[1024];
    int t = threadIdx.x;
    const u32* h = hist + (size_t)b * 65536;
    u32 s = 0;
    for (int k = 0; k < 64; k++) s += h[t * 64 + k];
    csum[t] = s;
    __syncthreads();
    if (t == 0) {
        u32 cum = 0;
        int bucket = 0;
        for (int c = 1023; c >= 0; c--) {
            if (cum + csum[c] >= (u32)PRE) {
                u32 cum2 = cum;
                for (int k = 63; k >= 0; k--) {
                    cum2 += h[c * 64 + k];
                    if (cum2 >= (u32)PRE) { bucket = c * 64 + k; break; }
                }
                break;
            }
            cum += csum[c];
        }
        thr[b] = (u32)bucket << 16;
    }
}

// ---------------- gated fallback: compact with exact threshold -----------------
__global__ void compact2_kernel(const u32* __restrict__ flag, const float* __restrict__ probs,
                                const u32* __restrict__ thr, u32* __restrict__ cntp,
                                u64* __restrict__ cand) {
    int b = blockIdx.y;
    if (flag[b * 64] == 0) return;
    __shared__ u32 lcnt;
    __shared__ u32 lbase;
    int tid = threadIdx.x;
    int a = blockIdx.x * 256 + tid;
    if (tid == 0) lcnt = 0;
    __syncthreads();
    float s = probs[((size_t)b * NA + a) * 2 + 1];
    u32 bits = __float_as_uint(s);
    int lpos = -1;
    if (bits >= thr[b]) lpos = (int)atomicAdd(&lcnt, 1u);
    __syncthreads();
    if (tid == 0) lbase = lcnt ? atomicAdd(&cntp[b * 64], lcnt) : 0u;
    __syncthreads();
    if (lpos >= 0) {
        u32 pos = lbase + (u32)lpos;
        if (pos < CAP)
            cand[(size_t)b * CAP + pos] = ((u64)bits << 32) | (u32)(~(u32)a);
    }
}

// ---------------- per-batch bitonic sort of candidate keys ---------------------
__global__ __launch_bounds__(1024) void sort_kernel(u64* __restrict__ cand, const u32* __restrict__ cntp) {
    __shared__ u64 keys[CAP];
    int b = blockIdx.x, tid = threadIdx.x;
    int n = (int)min(cntp[b * 64], (u32)CAP);
    u64* cb = cand + (size_t)b * CAP;
    for (int i = tid; i < CAP; i += 1024) keys[i] = (i < n) ? cb[i] : 0ULL;
    __syncthreads();
    for (int k = 2; k <= CAP; k <<= 1) {
        for (int j = k >> 1; j > 0; j >>= 1) {
            for (int i = tid; i < CAP; i += 1024) {
                int ixj = i ^ j;
                if (ixj > i) {
                    u64 x = keys[i], y = keys[ixj];
                    bool desc = ((i & k) == 0);
                    if (desc ? (x < y) : (x > y)) { keys[i] = y; keys[ixj] = x; }
                }
            }
            __syncthreads();
        }
    }
    for (int i = tid; i < PRE; i += 1024) cb[i] = keys[i];
}

// ---------------- fused lazy NMS: decode + segment tiles + serial scan ---------
// One block per batch, 1024 threads. Segments of 256 sorted rows:
//   A: suppress segment rows vs kept list (LDS, 4-way split, early break)
//   B: strict-upper 256x256 intra-segment bit tile via per-wave ballots
//   scan (wave 0): ffs over 8 alive words in registers; kept -> 8-lane LDS
//        row read + AND-clear; append box to kept list.
// Stops as soon as K==POST -> later segments never computed.
__global__ __launch_bounds__(1024) void nms_fused(const u64* __restrict__ cand,
                                                  const float* __restrict__ deltas,
                                                  const float* __restrict__ img_info,
                                                  float* __restrict__ out) {
    __shared__ float4 segBox[SEG];
    __shared__ float  segArea[SEG];
    __shared__ float4 keptBox[POST];
    __shared__ float  keptArea[POST];
    __shared__ u32    tile[SEG][8];
    __shared__ unsigned char aliveP[4][SEG];
    __shared__ u32    alivePack[8];
    __shared__ int    Kvar;

    int b = blockIdx.x;
    int t = threadIdx.x;
    if (t == 0) Kvar = 0;
    float hmax = __fsub_rn(img_info[b * 3 + 0], 1.0f);
    float wmax = __fsub_rn(img_info[b * 3 + 1], 1.0f);
    __syncthreads();

    for (int s = 0; s < NSEG; ++s) {
        int K0 = Kvar;
        if (K0 >= POST) break;                   // uniform

        // ---- decode segment + init alive
        if (t < SEG) {
            int g = s * SEG + t;
            float4 bx = make_float4(0.f, 0.f, 0.f, 0.f);
            float ar = 0.f;
            unsigned char alive = 0;
            if (g < PRE) {
                u64 key = cand[(size_t)b * CAP + g];
                bx = decode_box(key, b, deltas, hmax, wmax);
                ar = box_area(bx);
                alive = 1;
            }
            segBox[t] = bx;
            segArea[t] = ar;
            aliveP[0][t] = alive; aliveP[1][t] = alive;
            aliveP[2][t] = alive; aliveP[3][t] = alive;
        }
        __syncthreads();

        // ---- phase A: vs kept list (4-way split over threads)
        {
            int tt = t & (SEG - 1);
            int p  = t >> 8;                     // 0..3, uniform per wave
            int g  = s * SEG + tt;
            if (g < PRE && K0 > 0) {
                float4 rb = segBox[tt];
                float  ra = segArea[tt];
                unsigned char al = 1;
                for (int k = p; k < K0; k += 4) {
                    if (iou_supp(keptBox[k], keptArea[k], rb, ra)) { al = 0; break; }
                }
                if (!al) aliveP[p][tt] = 0;
            }
        }
        __syncthreads();

        // ---- phase B: strict-upper intra-segment tile
        {
            int w = t >> 6, lane = t & 63;
            int wc = w & 3, h = w >> 2;          // cols 64*wc+lane ; rows 64*h..+63
            int c = wc * 64 + lane;
            float4 cb = segBox[c];
            float  ca = segArea[c];
            int rlo = h * 64;
            for (int r = rlo; r < rlo + 64; ++r) {
                u64 bal = 0ULL;
                if (r < wc * 64 + 64) {          // uniform per wave
                    float4 rb2 = segBox[r];      // broadcast
                    float  ra2 = segArea[r];
                    bool bit = (r < c) && iou_supp(rb2, ra2, cb, ca);
                    bal = __ballot(bit);
                }
                if (lane == 0) tile[r][2 * wc]     = (u32)bal;
                if (lane == 1) tile[r][2 * wc + 1] = (u32)(bal >> 32);
            }
        }
        __syncthreads();

        // ---- pack alive bits (waves 0..3)
        if (t < SEG) {
            bool pred = aliveP[0][t] && aliveP[1][t] && aliveP[2][t] && aliveP[3][t];
            u64 bal = __ballot(pred);
            int w = t >> 6, lane = t & 63;
            if (lane == 0) alivePack[2 * w]     = (u32)bal;
            if (lane == 1) alivePack[2 * w + 1] = (u32)(bal >> 32);
        }
        __syncthreads();

        // ---- serial greedy scan (wave 0 only)
        if (t < 64) {
            int l = t;
            u32 va = (l < 8) ? alivePack[l] : 0u;
            int K = K0;
            while (true) {
                u64 balv = __ballot(va != 0u);
                if (balv == 0ULL) break;
                int wsel = __ffsll(balv) - 1;
                u32 word = __builtin_amdgcn_readlane(va, wsel);
                int r = (wsel << 5) + (__ffs(word) - 1);
                // append kept box (lanes 8-12) in the same LDS window as the
                // tile row read (lanes 0-7): one latency per kept row.
                u32 trow = tile[r][l & 7];
                if (l >= 8 && l < 12)
                    ((float*)keptBox)[K * 4 + (l - 8)] = ((const float*)segBox)[r * 4 + (l - 8)];
                if (l == 12) keptArea[K] = segArea[r];
                u32 self = (l == (r >> 5)) ? (1u << (r & 31)) : 0u;
                if (l < 8) va &= ~(trow | self);
                ++K;
                if (K == POST) break;
            }
            if (l == 0) Kvar = K;
        }
        __syncthreads();
    }

    // ---- epilogue: write output
    int K = Kvar;
    for (int s2 = t; s2 < POST; s2 += 1024) {
        float* o = out + ((size_t)b * POST + s2) * 5;
        if (s2 < K) {
            float4 bx = keptBox[s2];
            o[0] = (float)b; o[1] = bx.x; o[2] = bx.y; o[3] = bx.z; o[4] = bx.w;
        } else {
            o[0] = (float)b; o[1] = 0.f; o[2] = 0.f; o[3] = 0.f; o[4] = 0.f;
        }
    }
}

// ---------------- fallback: monolithic sort+decode+NMS (small ws) --------------
__global__ __launch_bounds__(1024) void final_kernel(const u64* __restrict__ cand, const u32* __restrict__ cntp,
                             const float* __restrict__ deltas, const float* __restrict__ img_info,
                             float* __restrict__ out) {
    __shared__ union {
        u64 keys[CAP];
        struct {
            float boxes[PRE][4];
            float areas[PRE];
            u32   alive[192];
        } n;
    } sh;
    __shared__ int s_next;

    int b = blockIdx.x;
    int tid = threadIdx.x;

    for (int s = tid; s < POST; s += 1024) {
        float* o = out + ((size_t)b * POST + s) * 5;
        o[0] = (float)b; o[1] = 0.f; o[2] = 0.f; o[3] = 0.f; o[4] = 0.f;
    }

    int n = (int)min(cntp[b * 64], (u32)CAP);
    for (int i = tid; i < CAP; i += 1024)
        sh.keys[i] = (i < n) ? cand[(size_t)b * CAP + i] : 0ULL;
    __syncthreads();

    for (int k = 2; k <= CAP; k <<= 1) {
        for (int j = k >> 1; j > 0; j >>= 1) {
            for (int i = tid; i < CAP; i += 1024) {
                int ixj = i ^ j;
                if (ixj > i) {
                    u64 x = sh.keys[i], y = sh.keys[ixj];
                    bool desc = ((i & k) == 0);
                    if (desc ? (x < y) : (x > y)) { sh.keys[i] = y; sh.keys[ixj] = x; }
                }
            }
            __syncthreads();
        }
    }

    u32 myIdx[6];
    #pragma unroll
    for (int r = 0; r < 6; r++) {
        int i = tid + r * 1024;
        if (i < PRE) myIdx[r] = ~(u32)(sh.keys[i]);
    }
    __syncthreads();

    float hmax = __fsub_rn(img_info[b * 3 + 0], 1.0f);
    float wmax = __fsub_rn(img_info[b * 3 + 1], 1.0f);

    #pragma unroll
    for (int r = 0; r < 6; r++) {
        int i = tid + r * 1024;
        if (i < PRE) {
            int a = (int)myIdx[r];
            float a0, a1, a2, a3;
            anchor_at(a, a0, a1, a2, a3);
            const float4 d4 = *(const float4*)(deltas + ((size_t)b * NA + a) * 4);
            float w  = __fadd_rn(__fsub_rn(a2, a0), 1.0f);
            float h  = __fadd_rn(__fsub_rn(a3, a1), 1.0f);
            float cx = __fadd_rn(a0, __fmul_rn(0.5f, w));
            float cy = __fadd_rn(a1, __fmul_rn(0.5f, h));
            float pcx = __fadd_rn(__fmul_rn(d4.x, w), cx);
            float pcy = __fadd_rn(__fmul_rn(d4.y, h), cy);
            float pw  = __fmul_rn((float)exp((double)d4.z), w);
            float ph  = __fmul_rn((float)exp((double)d4.w), h);
            float x1 = __fsub_rn(pcx, __fmul_rn(0.5f, pw));
            float y1 = __fsub_rn(pcy, __fmul_rn(0.5f, ph));
            float x2 = __fadd_rn(pcx, __fmul_rn(0.5f, pw));
            float y2 = __fadd_rn(pcy, __fmul_rn(0.5f, ph));
            x1 = fminf(fmaxf(x1, 0.f), wmax);
            x2 = fminf(fmaxf(x2, 0.f), wmax);
            y1 = fminf(fmaxf(y1, 0.f), hmax);
            y2 = fminf(fmaxf(y2, 0.f), hmax);
            sh.n.boxes[i][0] = x1; sh.n.boxes[i][1] = y1;
            sh.n.boxes[i][2] = x2; sh.n.boxes[i][3] = y2;
            sh.n.areas[i] = __fmul_rn(__fadd_rn(__fsub_rn(x2, x1), 1.0f),
                                      __fadd_rn(__fsub_rn(y2, y1), 1.0f));
        }
    }

    for (int wdi = tid; wdi < 192; wdi += 1024) {
        u32 v = 0xFFFFFFFFu;
        if (wdi == 187) v = 0x0000FFFFu;
        if (wdi > 187)  v = 0u;
        sh.n.alive[wdi] = v;
    }
    __syncthreads();

    int kept = 0;
    int scanWord = 0;
    while (kept < POST) {
        if (tid == 0) {
            int found = -1;
            while (scanWord < 188) {
                u32 wv = sh.n.alive[scanWord];
                if (wv) { found = scanWord * 32 + (__ffs(wv) - 1); break; }
                scanWord++;
            }
            s_next = found;
        }
        __syncthreads();
        int i = s_next;
        if (i < 0) break;
        float bx1 = sh.n.boxes[i][0], by1 = sh.n.boxes[i][1];
        float bx2 = sh.n.boxes[i][2], by2 = sh.n.boxes[i][3];
        float bar = sh.n.areas[i];
        if (tid == 0) {
            float* o = out + ((size_t)b * POST + kept) * 5;
            o[1] = bx1; o[2] = by1; o[3] = bx2; o[4] = by2;
            atomicAnd(&sh.n.alive[i >> 5], ~(1u << (i & 31)));
        }
        for (int j = i + 1 + tid; j < PRE; j += 1024) {
            float x1 = sh.n.boxes[j][0], y1 = sh.n.boxes[j][1];
            float x2 = sh.n.boxes[j][2], y2 = sh.n.boxes[j][3];
            float xx1 = fmaxf(x1, bx1), yy1 = fmaxf(y1, by1);
            float xx2 = fminf(x2, bx2), yy2 = fminf(y2, by2);
            float iw = fmaxf(__fadd_rn(__fsub_rn(xx2, xx1), 1.0f), 0.f);
            float ih = fmaxf(__fadd_rn(__fsub_rn(yy2, yy1), 1.0f), 0.f);
            float inter = __fmul_rn(iw, ih);
            float denom = __fsub_rn(__fadd_rn(sh.n.areas[j], bar), inter);
            float iou = __fdiv_rn(inter, denom);
            if (iou > 0.7f) atomicAnd(&sh.n.alive[j >> 5], ~(1u << (j & 31)));
        }
        kept++;
        __syncthreads();
    }
}

// ---------------- launcher -----------------------------------------------------
extern "C" void kernel_launch(void* const* d_in, const int* in_sizes, int n_in,
                              void* d_out, int out_size, void* d_ws, size_t ws_size,
                              hipStream_t stream) {
    const float* probs    = (const float*)d_in[0];
    const float* deltas   = (const float*)d_in[1];
    const float* img_info = (const float*)d_in[2];
    float* out = (float*)d_out;

    char* ws = (char*)d_ws;
    size_t off = 0;
    u32* cntp = (u32*)(ws + off); off += (size_t)NB * 64 * sizeof(u32);      // 4 KiB
    u32* flag = (u32*)(ws + off); off += (size_t)NB * 64 * sizeof(u32);      // 4 KiB
    u32* thr  = (u32*)(ws + off); off += 4096;
    u32* hist = (u32*)(ws + off); off += (size_t)NB * 65536 * sizeof(u32);   // 4 MiB
    u64* cand = (u64*)(ws + off); off += (size_t)NB * CAP * sizeof(u64);     // 1 MiB
    bool bigws = (ws_size >= off);

    dim3 gA((NA + 255) / 256, NB);

    hipMemsetAsync(cntp, 0, (size_t)NB * 64 * sizeof(u32), stream);

    if (bigws) {
        compact_fixed<<<gA, 256, 0, stream>>>(probs, cntp, cand);
        check_kernel<<<1, 64, 0, stream>>>(cntp, flag);
        // gated exact fallback (no-ops when all flags clean)
        zero_hist<<<dim3(256, NB), 256, 0, stream>>>(flag, hist);
        hist_kernel<<<gA, 256, 0, stream>>>(flag, probs, hist);
        thresh_kernel<<<NB, 1024, 0, stream>>>(flag, hist, thr);
        compact2_kernel<<<gA, 256, 0, stream>>>(flag, probs, thr, cntp, cand);
        // main pipeline
        sort_kernel<<<NB, 1024, 0, stream>>>(cand, cntp);
        nms_fused<<<NB, 1024, 0, stream>>>(cand, deltas, img_info, out);
    } else {
        hipMemsetAsync(flag, 1, (size_t)NB * 64 * sizeof(u32), stream);
        hipMemsetAsync(hist, 0, (size_t)NB * 65536 * sizeof(u32), stream);
        hist_kernel<<<gA, 256, 0, stream>>>(flag, probs, hist);
        thresh_kernel<<<NB, 1024, 0, stream>>>(flag, hist, thr);
        compact2_kernel<<<gA, 256, 0, stream>>>(flag, probs, thr, cntp, cand);
        final_kernel<<<NB, 1024, 0, stream>>>(cand, cntp, deltas, img_info, out);
    }
}

// Round 8
// 518.938 us; speedup vs baseline: 1.2255x; 1.0645x over previous
//
#include <hip/hip_runtime.h>

#define NB 16
#define NA 261888
#define PRE 6000
#define POST 1000
#define CAP 8192
#define SEG 256
#define NSEG ((PRE + SEG - 1) / SEG)   // 24
#define THRF 0.972f     // fixed fast-path threshold; E[cnt]=7333, 15.8 sigma > PRE, 10.2 sigma < CAP
// Exact NMS predicate: RN32(inter/denom) > 0.7f  <=>  inter >= MBOUND * denom
// MBOUND = midpoint(0.7f, nextafterf(0.7f,inf)) = 0x1.666667p-1 (bit24 set).
// 25-bit mantissa x 24-bit denom -> f64 product exact; tie q==M rounds to even
// (0x1.666668p-1) > 0.7f so ">=" is the correct inclusive test.
#define MBOUND 0x1.666667p-1

typedef unsigned int u32;
typedef unsigned long long u64;

__device__ __constant__ int NE_UNITS[10] = {0, 1, 2, 3, 5, 6, 7, 10, 11, 15};

__device__ inline float box_area(float4 v) {
    return __fmul_rn(__fadd_rn(__fsub_rn(v.z, v.x), 1.0f),
                     __fadd_rn(__fsub_rn(v.w, v.y), 1.0f));
}

__device__ inline bool iou_supp(float4 a, float aa, float4 c, float ca) {
    float xx1 = fmaxf(c.x, a.x);
    float yy1 = fmaxf(c.y, a.y);
    float xx2 = fminf(c.z, a.z);
    float yy2 = fminf(c.w, a.w);
    float iw = fmaxf(__fadd_rn(__fsub_rn(xx2, xx1), 1.0f), 0.f);
    float ih = fmaxf(__fadd_rn(__fsub_rn(yy2, yy1), 1.0f), 0.f);
    float inter = __fmul_rn(iw, ih);
    float denom = __fsub_rn(__fadd_rn(ca, aa), inter);
    return ((double)inter >= (double)MBOUND * (double)denom);
}

// ---------------- anchors (match numpy float64 -> float32 exactly) -------------
__device__ inline void anchor_at(int idx, float& a0, float& a1, float& a2, float& a3) {
    int base, fw, stride, scale;
    if (idx < 196608)      { base = 0;      fw = 256; stride = 4;  scale = 4; }
    else if (idx < 245760) { base = 196608; fw = 128; stride = 8;  scale = 8; }
    else if (idx < 258048) { base = 245760; fw = 64;  stride = 16; scale = 16; }
    else if (idx < 261120) { base = 258048; fw = 32;  stride = 32; scale = 32; }
    else                   { base = 261120; fw = 16;  stride = 64; scale = 64; }
    int rel  = idx - base;
    int ri   = rel % 3;
    int cell = rel / 3;
    int col  = cell & (fw - 1);
    int row  = cell / fw;
    double cx = (col + 0.5) * (double)stride;
    double cy = (row + 0.5) * (double)stride;
    double sz = (double)scale * 8.0;
    double sq = (ri == 0) ? 0.7071067811865476 : ((ri == 1) ? 1.0 : 1.4142135623730951);
    double wsd = sz * sq;
    double hsd = sz / sq;
    a0 = (float)(cx - 0.5 * wsd);
    a1 = (float)(cy - 0.5 * hsd);
    a2 = (float)(cx + 0.5 * wsd);
    a3 = (float)(cy + 0.5 * hsd);
}

__device__ inline float4 decode_box(u64 key, int b, const float* __restrict__ deltas,
                                    float hmax, float wmax) {
    int a = (int)(~(u32)key);
    float a0, a1, a2, a3;
    anchor_at(a, a0, a1, a2, a3);
    const float4 d4 = *(const float4*)(deltas + ((size_t)b * NA + a) * 4);
    float w  = __fadd_rn(__fsub_rn(a2, a0), 1.0f);
    float h  = __fadd_rn(__fsub_rn(a3, a1), 1.0f);
    float cx = __fadd_rn(a0, __fmul_rn(0.5f, w));
    float cy = __fadd_rn(a1, __fmul_rn(0.5f, h));
    float pcx = __fadd_rn(__fmul_rn(d4.x, w), cx);
    float pcy = __fadd_rn(__fmul_rn(d4.y, h), cy);
    float pw  = __fmul_rn((float)exp((double)d4.z), w);
    float ph  = __fmul_rn((float)exp((double)d4.w), h);
    float x1 = __fsub_rn(pcx, __fmul_rn(0.5f, pw));
    float y1 = __fsub_rn(pcy, __fmul_rn(0.5f, ph));
    float x2 = __fadd_rn(pcx, __fmul_rn(0.5f, pw));
    float y2 = __fadd_rn(pcy, __fmul_rn(0.5f, ph));
    x1 = fminf(fmaxf(x1, 0.f), wmax);
    x2 = fminf(fmaxf(x2, 0.f), wmax);
    y1 = fminf(fmaxf(y1, 0.f), hmax);
    y2 = fminf(fmaxf(y2, 0.f), hmax);
    return make_float4(x1, y1, x2, y2);
}

// ---------------- fast path: fixed-threshold compact, block-aggregated ---------
__global__ void compact_fixed(const float* __restrict__ probs, u32* __restrict__ cntp,
                              u64* __restrict__ cand) {
    __shared__ u32 lcnt;
    __shared__ u32 lbase;
    int tid = threadIdx.x;
    int a = blockIdx.x * 256 + tid;          // NA == 1023*256, no tail
    int b = blockIdx.y;
    if (tid == 0) lcnt = 0;
    __syncthreads();
    float2 pv = *(const float2*)(probs + ((size_t)b * NA + a) * 2);
    float s = pv.y;
    u32 bits = __float_as_uint(s);
    int lpos = -1;
    if (s >= THRF) lpos = (int)atomicAdd(&lcnt, 1u);
    __syncthreads();
    if (tid == 0) lbase = lcnt ? atomicAdd(&cntp[b * 64], lcnt) : 0u;
    __syncthreads();
    if (lpos >= 0) {
        u32 pos = lbase + (u32)lpos;
        if (pos < CAP)
            cand[(size_t)b * CAP + pos] = ((u64)bits << 32) | (u32)(~(u32)a);
    }
}

// ---------------- validate fast path; set per-batch fallback flags -------------
__global__ void check_kernel(u32* __restrict__ cntp, u32* __restrict__ flag) {
    int t = threadIdx.x;
    if (t < NB) {
        u32 c = cntp[t * 64];
        u32 bad = (c < (u32)PRE || c > (u32)CAP) ? 1u : 0u;
        flag[t * 64] = bad;
        if (bad) cntp[t * 64] = 0;   // fallback compact restarts from 0
    }
}

// ---------------- gated fallback: zero hist ------------------------------------
__global__ void zero_hist(const u32* __restrict__ flag, u32* __restrict__ hist) {
    int b = blockIdx.y;
    if (flag[b * 64] == 0) return;
    int i = blockIdx.x * 256 + threadIdx.x;
    hist[(size_t)b * 65536 + i] = 0;
}

// ---------------- gated fallback: histogram of score bits (top 16) -------------
__global__ void hist_kernel(const u32* __restrict__ flag, const float* __restrict__ probs,
                            u32* __restrict__ hist) {
    int b = blockIdx.y;
    if (flag[b * 64] == 0) return;
    int a = blockIdx.x * 256 + threadIdx.x;
    float2 pv = *(const float2*)(probs + ((size_t)b * NA + a) * 2);
    u32 bits = __float_as_uint(pv.y);
    atomicAdd(&hist[(size_t)b * 65536 + (bits >> 16)], 1u);
}

// ---------------- gated fallback: per-batch threshold --------------------------
__global__ __launch_bounds__(1024) void thresh_kernel(const u32* __restrict__ flag,
                                                      const u32* __restrict__ hist,
                                                      u32* __restrict__ thr) {
    int b = blockIdx.x;
    if (flag[b * 64] == 0) return;
    __shared__ u32 csum[1024];
    int t = threadIdx.x;
    const u32* h = hist + (size_t)b * 65536;
    u32 s = 0;
    for (int k = 0; k < 64; k++) s += h[t * 64 + k];
    csum[t] = s;
    __syncthreads();
    if (t == 0) {
        u32 cum = 0;
        int bucket = 0;
        for (int c = 1023; c >= 0; c--) {
            if (cum + csum[c] >= (u32)PRE) {
                u32 cum2 = cum;
                for (int k = 63; k >= 0; k--) {
                    cum2 += h[c * 64 + k];
                    if (cum2 >= (u32)PRE) { bucket = c * 64 + k; break; }
                }
                break;
            }
            cum += csum[c];
        }
        thr[b] = (u32)bucket << 16;
    }
}

// ---------------- gated fallback: compact with exact threshold -----------------
__global__ void compact2_kernel(const u32* __restrict__ flag, const float* __restrict__ probs,
                                const u32* __restrict__ thr, u32* __restrict__ cntp,
                                u64* __restrict__ cand) {
    int b = blockIdx.y;
    if (flag[b * 64] == 0) return;
    __shared__ u32 lcnt;
    __shared__ u32 lbase;
    int tid = threadIdx.x;
    int a = blockIdx.x * 256 + tid;
    if (tid == 0) lcnt = 0;
    __syncthreads();
    float2 pv = *(const float2*)(probs + ((size_t)b * NA + a) * 2);
    u32 bits = __float_as_uint(pv.y);
    int lpos = -1;
    if (bits >= thr[b]) lpos = (int)atomicAdd(&lcnt, 1u);
    __syncthreads();
    if (tid == 0) lbase = lcnt ? atomicAdd(&cntp[b * 64], lcnt) : 0u;
    __syncthreads();
    if (lpos >= 0) {
        u32 pos = lbase + (u32)lpos;
        if (pos < CAP)
            cand[(size_t)b * CAP + pos] = ((u64)bits << 32) | (u32)(~(u32)a);
    }
}

// ---------------- per-batch bitonic sort of candidate keys ---------------------
__global__ __launch_bounds__(1024) void sort_kernel(u64* __restrict__ cand, const u32* __restrict__ cntp) {
    __shared__ u64 keys[CAP];
    int b = blockIdx.x, tid = threadIdx.x;
    int n = (int)min(cntp[b * 64], (u32)CAP);
    u64* cb = cand + (size_t)b * CAP;
    for (int i = tid; i < CAP; i += 1024) keys[i] = (i < n) ? cb[i] : 0ULL;
    __syncthreads();
    for (int k = 2; k <= CAP; k <<= 1) {
        for (int j = k >> 1; j > 0; j >>= 1) {
            for (int i = tid; i < CAP; i += 1024) {
                int ixj = i ^ j;
                if (ixj > i) {
                    u64 x = keys[i], y = keys[ixj];
                    bool desc = ((i & k) == 0);
                    if (desc ? (x < y) : (x > y)) { keys[i] = y; keys[ixj] = x; }
                }
            }
            __syncthreads();
        }
    }
    for (int i = tid; i < PRE; i += 1024) cb[i] = keys[i];
}

// ---------------- pipelined fused lazy NMS -------------------------------------
// One block per batch, 1024 threads, double-buffered segments of 256 rows.
// Per iteration: [barrier] phase3(seg s: combine aliveB + residual new kepts +
// pack aliveW) merged with decode(seg s+1) [barrier] then CONCURRENTLY:
//   wave 0: serial greedy scan of seg s (tile + aliveW, appends kept K->K1)
//   waves 1-15: phase A of seg s+1 vs kept[0..K) -> aliveB; intra-tile build.
// Stops when K==POST; later segments never computed.
__global__ __launch_bounds__(1024) void nms_fused(const u64* __restrict__ cand,
                                                  const float* __restrict__ deltas,
                                                  const float* __restrict__ img_info,
                                                  float* __restrict__ out) {
    __shared__ float4 segBox[2][SEG];
    __shared__ float  segArea[2][SEG];
    __shared__ u32    tile[2][SEG][8];
    __shared__ u32    aliveW[2][8];
    __shared__ unsigned char aliveB[2][4][SEG];
    __shared__ float4 keptBox[POST];
    __shared__ float  keptArea[POST];
    __shared__ int    Kvar;

    int b = blockIdx.x;
    int t = threadIdx.x;
    int lane = t & 63;
    int w = t >> 6;
    if (t == 0) Kvar = 0;
    float hmax = __fsub_rn(img_info[b * 3 + 0], 1.0f);
    float wmax = __fsub_rn(img_info[b * 3 + 1], 1.0f);

    // ---- prolog: decode segment 0
    if (t < SEG) {
        u64 key = cand[(size_t)b * CAP + t];
        float4 bx = decode_box(key, b, deltas, hmax, wmax);
        segBox[0][t] = bx;
        segArea[0][t] = box_area(bx);
    }
    __syncthreads();
    // tile for seg 0 (waves 0..9) + pack aliveW[0] (all rows valid)
    if (w < 10) {
        int u = NE_UNITS[w];
        int wc = u & 3, h = u >> 2;
        int c = wc * 64 + lane;
        float4 cb = segBox[0][c];
        float  ca = segArea[0][c];
        for (int r = h * 64; r < h * 64 + 64; ++r) {
            float4 rb = segBox[0][r];
            float  ra = segArea[0][r];
            bool bit = (r < c) && iou_supp(rb, ra, cb, ca);
            u64 bal = __ballot(bit);
            if (lane == 0) tile[0][r][2 * wc]     = (u32)bal;
            if (lane == 1) tile[0][r][2 * wc + 1] = (u32)(bal >> 32);
        }
    }
    if (t < SEG) {
        u64 bal = __ballot(true);
        if (lane == 0) aliveW[0][2 * w]     = (u32)bal;
        if (lane == 1) aliveW[0][2 * w + 1] = (u32)(bal >> 32);
    }

    int Kprev = 0;
    for (int s = 0; s < NSEG; ++s) {
        int bufc = s & 1, bufn = bufc ^ 1;
        __syncthreads();                       // barrier A
        int Kcur = Kvar;
        if (Kcur >= POST) break;               // uniform

        // ---- merged region: phase3(seg s) + decode(seg s+1)
        if (t < SEG) {
            if (s > 0) {
                bool al = aliveB[bufc][0][t] && aliveB[bufc][1][t] &&
                          aliveB[bufc][2][t] && aliveB[bufc][3][t];
                if (al && Kcur > Kprev) {
                    float4 rb = segBox[bufc][t];
                    float  ra = segArea[bufc][t];
                    for (int k = Kprev; k < Kcur; ++k)
                        if (iou_supp(keptBox[k], keptArea[k], rb, ra)) { al = false; break; }
                }
                u64 bal = __ballot(al);
                if (lane == 0) aliveW[bufc][2 * w]     = (u32)bal;
                if (lane == 1) aliveW[bufc][2 * w + 1] = (u32)(bal >> 32);
            }
            if (s + 1 < NSEG) {
                int g = (s + 1) * SEG + t;
                float4 bx = make_float4(0.f, 0.f, 0.f, 0.f);
                float ar = 0.f;
                bool valid = (g < PRE);
                if (valid) {
                    u64 key = cand[(size_t)b * CAP + g];
                    bx = decode_box(key, b, deltas, hmax, wmax);
                    ar = box_area(bx);
                }
                segBox[bufn][t] = bx;
                segArea[bufn][t] = ar;
                unsigned char v8 = valid ? 1 : 0;
                aliveB[bufn][0][t] = v8; aliveB[bufn][1][t] = v8;
                aliveB[bufn][2][t] = v8; aliveB[bufn][3][t] = v8;
            }
        }
        __syncthreads();                       // barrier B

        if (w == 0) {
            // ---- serial greedy scan of segment s (wave 0)
            int l = lane;
            u32 va = (l < 8) ? aliveW[bufc][l] : 0u;
            int KK = Kcur;
            while (true) {
                u64 balv = __ballot(va != 0u);
                if (balv == 0ULL) break;
                int wsel = __ffsll(balv) - 1;
                u32 word = __builtin_amdgcn_readlane(va, wsel);
                int r = (wsel << 5) + (__ffs(word) - 1);
                u32 trow = tile[bufc][r][l & 7];
                if (l >= 8 && l < 12)
                    ((float*)keptBox)[KK * 4 + (l - 8)] = ((const float*)segBox[bufc])[r * 4 + (l - 8)];
                if (l == 12) keptArea[KK] = segArea[bufc][r];
                u32 self = (l == (r >> 5)) ? (1u << (r & 31)) : 0u;
                if (l < 8) va &= ~(trow | self);
                ++KK;
                if (KK == POST) break;
            }
            if (l == 0) Kvar = KK;
        } else if (s + 1 < NSEG) {
            // ---- phase A for segment s+1 vs kept[0..Kcur)
            int v = t - 64;
            int row, p, step;
            if (v < 768) { row = v & 255; p = v >> 8; step = (row < 192) ? 4 : 3; }
            else         { row = v - 768; p = 3; step = 4; }
            if (aliveB[bufn][p][row] && Kcur > 0) {
                float4 rb = segBox[bufn][row];
                float  ra = segArea[bufn][row];
                for (int k = p; k < Kcur; k += step)
                    if (iou_supp(keptBox[k], keptArea[k], rb, ra)) {
                        aliveB[bufn][p][row] = 0; break;
                    }
            }
            // ---- intra-segment tile build for s+1 (waves 1..10)
            if (w <= 10) {
                int u = NE_UNITS[w - 1];
                int wc = u & 3, h = u >> 2;
                int c = wc * 64 + lane;
                float4 cb = segBox[bufn][c];
                float  ca = segArea[bufn][c];
                for (int r = h * 64; r < h * 64 + 64; ++r) {
                    float4 rb = segBox[bufn][r];
                    float  ra = segArea[bufn][r];
                    bool bit = (r < c) && iou_supp(rb, ra, cb, ca);
                    u64 bal = __ballot(bit);
                    if (lane == 0) tile[bufn][r][2 * wc]     = (u32)bal;
                    if (lane == 1) tile[bufn][r][2 * wc + 1] = (u32)(bal >> 32);
                }
            }
        }
        Kprev = Kcur;
    }
    __syncthreads();

    // ---- epilogue: write output
    int K = Kvar;
    for (int s2 = t; s2 < POST; s2 += 1024) {
        float* o = out + ((size_t)b * POST + s2) * 5;
        if (s2 < K) {
            float4 bx = keptBox[s2];
            o[0] = (float)b; o[1] = bx.x; o[2] = bx.y; o[3] = bx.z; o[4] = bx.w;
        } else {
            o[0] = (float)b; o[1] = 0.f; o[2] = 0.f; o[3] = 0.f; o[4] = 0.f;
        }
    }
}

// ---------------- fallback: monolithic sort+decode+NMS (small ws) --------------
__global__ __launch_bounds__(1024) void final_kernel(const u64* __restrict__ cand, const u32* __restrict__ cntp,
                             const float* __restrict__ deltas, const float* __restrict__ img_info,
                             float* __restrict__ out) {
    __shared__ union {
        u64 keys[CAP];
        struct {
            float boxes[PRE][4];
            float areas[PRE];
            u32   alive[192];
        } n;
    } sh;
    __shared__ int s_next;

    int b = blockIdx.x;
    int tid = threadIdx.x;

    for (int s = tid; s < POST; s += 1024) {
        float* o = out + ((size_t)b * POST + s) * 5;
        o[0] = (float)b; o[1] = 0.f; o[2] = 0.f; o[3] = 0.f; o[4] = 0.f;
    }

    int n = (int)min(cntp[b * 64], (u32)CAP);
    for (int i = tid; i < CAP; i += 1024)
        sh.keys[i] = (i < n) ? cand[(size_t)b * CAP + i] : 0ULL;
    __syncthreads();

    for (int k = 2; k <= CAP; k <<= 1) {
        for (int j = k >> 1; j > 0; j >>= 1) {
            for (int i = tid; i < CAP; i += 1024) {
                int ixj = i ^ j;
                if (ixj > i) {
                    u64 x = sh.keys[i], y = sh.keys[ixj];
                    bool desc = ((i & k) == 0);
                    if (desc ? (x < y) : (x > y)) { sh.keys[i] = y; sh.keys[ixj] = x; }
                }
            }
            __syncthreads();
        }
    }

    u32 myIdx[6];
    #pragma unroll
    for (int r = 0; r < 6; r++) {
        int i = tid + r * 1024;
        if (i < PRE) myIdx[r] = ~(u32)(sh.keys[i]);
    }
    __syncthreads();

    float hmax = __fsub_rn(img_info[b * 3 + 0], 1.0f);
    float wmax = __fsub_rn(img_info[b * 3 + 1], 1.0f);

    #pragma unroll
    for (int r = 0; r < 6; r++) {
        int i = tid + r * 1024;
        if (i < PRE) {
            int a = (int)myIdx[r];
            float a0, a1, a2, a3;
            anchor_at(a, a0, a1, a2, a3);
            const float4 d4 = *(const float4*)(deltas + ((size_t)b * NA + a) * 4);
            float w  = __fadd_rn(__fsub_rn(a2, a0), 1.0f);
            float h  = __fadd_rn(__fsub_rn(a3, a1), 1.0f);
            float cx = __fadd_rn(a0, __fmul_rn(0.5f, w));
            float cy = __fadd_rn(a1, __fmul_rn(0.5f, h));
            float pcx = __fadd_rn(__fmul_rn(d4.x, w), cx);
            float pcy = __fadd_rn(__fmul_rn(d4.y, h), cy);
            float pw  = __fmul_rn((float)exp((double)d4.z), w);
            float ph  = __fmul_rn((float)exp((double)d4.w), h);
            float x1 = __fsub_rn(pcx, __fmul_rn(0.5f, pw));
            float y1 = __fsub_rn(pcy, __fmul_rn(0.5f, ph));
            float x2 = __fadd_rn(pcx, __fmul_rn(0.5f, pw));
            float y2 = __fadd_rn(pcy, __fmul_rn(0.5f, ph));
            x1 = fminf(fmaxf(x1, 0.f), wmax);
            x2 = fminf(fmaxf(x2, 0.f), wmax);
            y1 = fminf(fmaxf(y1, 0.f), hmax);
            y2 = fminf(fmaxf(y2, 0.f), hmax);
            sh.n.boxes[i][0] = x1; sh.n.boxes[i][1] = y1;
            sh.n.boxes[i][2] = x2; sh.n.boxes[i][3] = y2;
            sh.n.areas[i] = __fmul_rn(__fadd_rn(__fsub_rn(x2, x1), 1.0f),
                                      __fadd_rn(__fsub_rn(y2, y1), 1.0f));
        }
    }

    for (int wdi = tid; wdi < 192; wdi += 1024) {
        u32 v = 0xFFFFFFFFu;
        if (wdi == 187) v = 0x0000FFFFu;
        if (wdi > 187)  v = 0u;
        sh.n.alive[wdi] = v;
    }
    __syncthreads();

    int kept = 0;
    int scanWord = 0;
    while (kept < POST) {
        if (tid == 0) {
            int found = -1;
            while (scanWord < 188) {
                u32 wv = sh.n.alive[scanWord];
                if (wv) { found = scanWord * 32 + (__ffs(wv) - 1); break; }
                scanWord++;
            }
            s_next = found;
        }
        __syncthreads();
        int i = s_next;
        if (i < 0) break;
        float bx1 = sh.n.boxes[i][0], by1 = sh.n.boxes[i][1];
        float bx2 = sh.n.boxes[i][2], by2 = sh.n.boxes[i][3];
        float bar = sh.n.areas[i];
        if (tid == 0) {
            float* o = out + ((size_t)b * POST + kept) * 5;
            o[1] = bx1; o[2] = by1; o[3] = bx2; o[4] = by2;
            atomicAnd(&sh.n.alive[i >> 5], ~(1u << (i & 31)));
        }
        for (int j = i + 1 + tid; j < PRE; j += 1024) {
            float x1 = sh.n.boxes[j][0], y1 = sh.n.boxes[j][1];
            float x2 = sh.n.boxes[j][2], y2 = sh.n.boxes[j][3];
            float xx1 = fmaxf(x1, bx1), yy1 = fmaxf(y1, by1);
            float xx2 = fminf(x2, bx2), yy2 = fminf(y2, by2);
            float iw = fmaxf(__fadd_rn(__fsub_rn(xx2, xx1), 1.0f), 0.f);
            float ih = fmaxf(__fadd_rn(__fsub_rn(yy2, yy1), 1.0f), 0.f);
            float inter = __fmul_rn(iw, ih);
            float denom = __fsub_rn(__fadd_rn(sh.n.areas[j], bar), inter);
            float iou = __fdiv_rn(inter, denom);
            if (iou > 0.7f) atomicAnd(&sh.n.alive[j >> 5], ~(1u << (j & 31)));
        }
        kept++;
        __syncthreads();
    }
}

// ---------------- launcher -----------------------------------------------------
extern "C" void kernel_launch(void* const* d_in, const int* in_sizes, int n_in,
                              void* d_out, int out_size, void* d_ws, size_t ws_size,
                              hipStream_t stream) {
    const float* probs    = (const float*)d_in[0];
    const float* deltas   = (const float*)d_in[1];
    const float* img_info = (const float*)d_in[2];
    float* out = (float*)d_out;

    char* ws = (char*)d_ws;
    size_t off = 0;
    u32* cntp = (u32*)(ws + off); off += (size_t)NB * 64 * sizeof(u32);      // 4 KiB
    u32* flag = (u32*)(ws + off); off += (size_t)NB * 64 * sizeof(u32);      // 4 KiB
    u32* thr  = (u32*)(ws + off); off += 4096;
    u32* hist = (u32*)(ws + off); off += (size_t)NB * 65536 * sizeof(u32);   // 4 MiB
    u64* cand = (u64*)(ws + off); off += (size_t)NB * CAP * sizeof(u64);     // 1 MiB
    bool bigws = (ws_size >= off);

    dim3 gA((NA + 255) / 256, NB);

    hipMemsetAsync(cntp, 0, (size_t)NB * 64 * sizeof(u32), stream);

    if (bigws) {
        compact_fixed<<<gA, 256, 0, stream>>>(probs, cntp, cand);
        check_kernel<<<1, 64, 0, stream>>>(cntp, flag);
        // gated exact fallback (no-ops when all flags clean)
        zero_hist<<<dim3(256, NB), 256, 0, stream>>>(flag, hist);
        hist_kernel<<<gA, 256, 0, stream>>>(flag, probs, hist);
        thresh_kernel<<<NB, 1024, 0, stream>>>(flag, hist, thr);
        compact2_kernel<<<gA, 256, 0, stream>>>(flag, probs, thr, cntp, cand);
        // main pipeline
        sort_kernel<<<NB, 1024, 0, stream>>>(cand, cntp);
        nms_fused<<<NB, 1024, 0, stream>>>(cand, deltas, img_info, out);
    } else {
        hipMemsetAsync(flag, 1, (size_t)NB * 64 * sizeof(u32), stream);
        hipMemsetAsync(hist, 0, (size_t)NB * 65536 * sizeof(u32), stream);
        hist_kernel<<<gA, 256, 0, stream>>>(flag, probs, hist);
        thresh_kernel<<<NB, 1024, 0, stream>>>(flag, hist, thr);
        compact2_kernel<<<gA, 256, 0, stream>>>(flag, probs, thr, cntp, cand);
        final_kernel<<<NB, 1024, 0, stream>>>(cand, cntp, deltas, img_info, out);
    }
}

// Round 9
// 517.614 us; speedup vs baseline: 1.2287x; 1.0026x over previous
//
#include <hip/hip_runtime.h>

#define NB 16
#define NA 261888
#define PRE 6000
#define POST 1000
#define CAP 8192
#define SEG 256
#define NSEG ((PRE + SEG - 1) / SEG)   // 24
#define KPAD 1024       // kept arrays padded so unguarded quad loads stay in-bounds
#define THRF 0.972f     // fixed fast-path threshold; E[cnt]=7333, 15.8 sigma > PRE, 10.2 sigma < CAP
// Exact NMS predicate: RN32(inter/denom) > 0.7f  <=>  inter >= MBOUND * denom
// MBOUND = midpoint(0.7f, nextafterf(0.7f,inf)) = 0x1.666667p-1 (bit24 set).
// 25-bit mantissa x 24-bit denom -> f64 product exact; tie q==M rounds to even
// (0x1.666668p-1) > 0.7f so ">=" is the correct inclusive test.
#define MBOUND 0x1.666667p-1

typedef unsigned int u32;
typedef unsigned long long u64;

__device__ __constant__ int NE_UNITS[10] = {0, 1, 2, 3, 5, 6, 7, 10, 11, 15};
__device__ __constant__ int TILE_N[3] = {4, 3, 3};
__device__ __constant__ int TILE_U[3][4] = {{0, 5, 10, 15}, {1, 2, 6, 0}, {3, 7, 11, 0}};

__device__ inline float box_area(float4 v) {
    return __fmul_rn(__fadd_rn(__fsub_rn(v.z, v.x), 1.0f),
                     __fadd_rn(__fsub_rn(v.w, v.y), 1.0f));
}

__device__ inline bool iou_supp(float4 a, float aa, float4 c, float ca) {
    float xx1 = fmaxf(c.x, a.x);
    float yy1 = fmaxf(c.y, a.y);
    float xx2 = fminf(c.z, a.z);
    float yy2 = fminf(c.w, a.w);
    float iw = fmaxf(__fadd_rn(__fsub_rn(xx2, xx1), 1.0f), 0.f);
    float ih = fmaxf(__fadd_rn(__fsub_rn(yy2, yy1), 1.0f), 0.f);
    float inter = __fmul_rn(iw, ih);
    float denom = __fsub_rn(__fadd_rn(ca, aa), inter);
    return ((double)inter >= (double)MBOUND * (double)denom);
}

// ---------------- anchors (match numpy float64 -> float32 exactly) -------------
__device__ inline void anchor_at(int idx, float& a0, float& a1, float& a2, float& a3) {
    int base, fw, stride, scale;
    if (idx < 196608)      { base = 0;      fw = 256; stride = 4;  scale = 4; }
    else if (idx < 245760) { base = 196608; fw = 128; stride = 8;  scale = 8; }
    else if (idx < 258048) { base = 245760; fw = 64;  stride = 16; scale = 16; }
    else if (idx < 261120) { base = 258048; fw = 32;  stride = 32; scale = 32; }
    else                   { base = 261120; fw = 16;  stride = 64; scale = 64; }
    int rel  = idx - base;
    int ri   = rel % 3;
    int cell = rel / 3;
    int col  = cell & (fw - 1);
    int row  = cell / fw;
    double cx = (col + 0.5) * (double)stride;
    double cy = (row + 0.5) * (double)stride;
    double sz = (double)scale * 8.0;
    double sq = (ri == 0) ? 0.7071067811865476 : ((ri == 1) ? 1.0 : 1.4142135623730951);
    double wsd = sz * sq;
    double hsd = sz / sq;
    a0 = (float)(cx - 0.5 * wsd);
    a1 = (float)(cy - 0.5 * hsd);
    a2 = (float)(cx + 0.5 * wsd);
    a3 = (float)(cy + 0.5 * hsd);
}

__device__ inline float4 decode_box(u64 key, int b, const float* __restrict__ deltas,
                                    float hmax, float wmax) {
    int a = (int)(~(u32)key);
    float a0, a1, a2, a3;
    anchor_at(a, a0, a1, a2, a3);
    const float4 d4 = *(const float4*)(deltas + ((size_t)b * NA + a) * 4);
    float w  = __fadd_rn(__fsub_rn(a2, a0), 1.0f);
    float h  = __fadd_rn(__fsub_rn(a3, a1), 1.0f);
    float cx = __fadd_rn(a0, __fmul_rn(0.5f, w));
    float cy = __fadd_rn(a1, __fmul_rn(0.5f, h));
    float pcx = __fadd_rn(__fmul_rn(d4.x, w), cx);
    float pcy = __fadd_rn(__fmul_rn(d4.y, h), cy);
    float pw  = __fmul_rn((float)exp((double)d4.z), w);
    float ph  = __fmul_rn((float)exp((double)d4.w), h);
    float x1 = __fsub_rn(pcx, __fmul_rn(0.5f, pw));
    float y1 = __fsub_rn(pcy, __fmul_rn(0.5f, ph));
    float x2 = __fadd_rn(pcx, __fmul_rn(0.5f, pw));
    float y2 = __fadd_rn(pcy, __fmul_rn(0.5f, ph));
    x1 = fminf(fmaxf(x1, 0.f), wmax);
    x2 = fminf(fmaxf(x2, 0.f), wmax);
    y1 = fminf(fmaxf(y1, 0.f), hmax);
    y2 = fminf(fmaxf(y2, 0.f), hmax);
    return make_float4(x1, y1, x2, y2);
}

// ---------------- fast path: fixed-threshold compact, block-aggregated ---------
__global__ void compact_fixed(const float* __restrict__ probs, u32* __restrict__ cntp,
                              u64* __restrict__ cand) {
    __shared__ u32 lcnt;
    __shared__ u32 lbase;
    int tid = threadIdx.x;
    int a = blockIdx.x * 256 + tid;          // NA == 1023*256, no tail
    int b = blockIdx.y;
    if (tid == 0) lcnt = 0;
    __syncthreads();
    float2 pv = *(const float2*)(probs + ((size_t)b * NA + a) * 2);
    float s = pv.y;
    u32 bits = __float_as_uint(s);
    int lpos = -1;
    if (s >= THRF) lpos = (int)atomicAdd(&lcnt, 1u);
    __syncthreads();
    if (tid == 0) lbase = lcnt ? atomicAdd(&cntp[b * 64], lcnt) : 0u;
    __syncthreads();
    if (lpos >= 0) {
        u32 pos = lbase + (u32)lpos;
        if (pos < CAP)
            cand[(size_t)b * CAP + pos] = ((u64)bits << 32) | (u32)(~(u32)a);
    }
}

// ---------------- validate fast path; set per-batch fallback flags -------------
__global__ void check_kernel(u32* __restrict__ cntp, u32* __restrict__ flag) {
    int t = threadIdx.x;
    if (t < NB) {
        u32 c = cntp[t * 64];
        u32 bad = (c < (u32)PRE || c > (u32)CAP) ? 1u : 0u;
        flag[t * 64] = bad;
        if (bad) cntp[t * 64] = 0;   // fallback compact restarts from 0
    }
}

// ---------------- gated fallback: zero hist ------------------------------------
__global__ void zero_hist(const u32* __restrict__ flag, u32* __restrict__ hist) {
    int b = blockIdx.y;
    if (flag[b * 64] == 0) return;
    int i = blockIdx.x * 256 + threadIdx.x;
    hist[(size_t)b * 65536 + i] = 0;
}

// ---------------- gated fallback: histogram of score bits (top 16) -------------
__global__ void hist_kernel(const u32* __restrict__ flag, const float* __restrict__ probs,
                            u32* __restrict__ hist) {
    int b = blockIdx.y;
    if (flag[b * 64] == 0) return;
    int a = blockIdx.x * 256 + threadIdx.x;
    float2 pv = *(const float2*)(probs + ((size_t)b * NA + a) * 2);
    u32 bits = __float_as_uint(pv.y);
    atomicAdd(&hist[(size_t)b * 65536 + (bits >> 16)], 1u);
}

// ---------------- gated fallback: per-batch threshold --------------------------
__global__ __launch_bounds__(1024) void thresh_kernel(const u32* __restrict__ flag,
                                                      const u32* __restrict__ hist,
                                                      u32* __restrict__ thr) {
    int b = blockIdx.x;
    if (flag[b * 64] == 0) return;
    __shared__ u32 csum[1024];
    int t = threadIdx.x;
    const u32* h = hist + (size_t)b * 65536;
    u32 s = 0;
    for (int k = 0; k < 64; k++) s += h[t * 64 + k];
    csum[t] = s;
    __syncthreads();
    if (t == 0) {
        u32 cum = 0;
        int bucket = 0;
        for (int c = 1023; c >= 0; c--) {
            if (cum + csum[c] >= (u32)PRE) {
                u32 cum2 = cum;
                for (int k = 63; k >= 0; k--) {
                    cum2 += h[c * 64 + k];
                    if (cum2 >= (u32)PRE) { bucket = c * 64 + k; break; }
                }
                break;
            }
            cum += csum[c];
        }
        thr[b] = (u32)bucket << 16;
    }
}

// ---------------- gated fallback: compact with exact threshold -----------------
__global__ void compact2_kernel(const u32* __restrict__ flag, const float* __restrict__ probs,
                                const u32* __restrict__ thr, u32* __restrict__ cntp,
                                u64* __restrict__ cand) {
    int b = blockIdx.y;
    if (flag[b * 64] == 0) return;
    __shared__ u32 lcnt;
    __shared__ u32 lbase;
    int tid = threadIdx.x;
    int a = blockIdx.x * 256 + tid;
    if (tid == 0) lcnt = 0;
    __syncthreads();
    float2 pv = *(const float2*)(probs + ((size_t)b * NA + a) * 2);
    u32 bits = __float_as_uint(pv.y);
    int lpos = -1;
    if (bits >= thr[b]) lpos = (int)atomicAdd(&lcnt, 1u);
    __syncthreads();
    if (tid == 0) lbase = lcnt ? atomicAdd(&cntp[b * 64], lcnt) : 0u;
    __syncthreads();
    if (lpos >= 0) {
        u32 pos = lbase + (u32)lpos;
        if (pos < CAP)
            cand[(size_t)b * CAP + pos] = ((u64)bits << 32) | (u32)(~(u32)a);
    }
}

// ---------------- per-batch bitonic sort of candidate keys ---------------------
__global__ __launch_bounds__(1024) void sort_kernel(u64* __restrict__ cand, const u32* __restrict__ cntp) {
    __shared__ u64 keys[CAP];
    int b = blockIdx.x, tid = threadIdx.x;
    int n = (int)min(cntp[b * 64], (u32)CAP);
    u64* cb = cand + (size_t)b * CAP;
    for (int i = tid; i < CAP; i += 1024) keys[i] = (i < n) ? cb[i] : 0ULL;
    __syncthreads();
    for (int k = 2; k <= CAP; k <<= 1) {
        for (int j = k >> 1; j > 0; j >>= 1) {
            for (int i = tid; i < CAP; i += 1024) {
                int ixj = i ^ j;
                if (ixj > i) {
                    u64 x = keys[i], y = keys[ixj];
                    bool desc = ((i & k) == 0);
                    if (desc ? (x < y) : (x > y)) { keys[i] = y; keys[ixj] = x; }
                }
            }
            __syncthreads();
        }
    }
    for (int i = tid; i < PRE; i += 1024) cb[i] = keys[i];
}

// ---------------- pipelined fused lazy NMS -------------------------------------
// One block per batch, 1024 threads, double-buffered segments of 256 rows.
// Wave roles per iteration (after barrier B):
//   wave 0     : serial greedy scan of seg s (tile + aliveW, appends kept)
//   waves 1-12 : phase A of seg s+1 vs kept[0..Kcur): (rowgroup rg = (w-1)&3,
//                keptchunk kc = (w-1)>>2, k = kc+3j). k is WAVE-UNIFORM ->
//                keptBox[k] reads broadcast; quad-unrolled, no break inside a
//                quad -> loads pipeline. All-dead ballot exit every 8 quads.
//   waves 13-15: strict-upper intra-segment 256x256 bit tile for seg s+1.
// Stops when K==POST; later segments never computed.
__global__ __launch_bounds__(1024) void nms_fused(const u64* __restrict__ cand,
                                                  const float* __restrict__ deltas,
                                                  const float* __restrict__ img_info,
                                                  float* __restrict__ out) {
    __shared__ float4 segBox[2][SEG];
    __shared__ float  segArea[2][SEG];
    __shared__ u32    tile[2][SEG][8];
    __shared__ u32    aliveW[2][8];
    __shared__ unsigned char aliveB[2][3][SEG];
    __shared__ float4 keptBox[KPAD];
    __shared__ float  keptArea[KPAD];
    __shared__ int    Kvar;

    int b = blockIdx.x;
    int t = threadIdx.x;
    int lane = t & 63;
    int w = t >> 6;
    if (t == 0) Kvar = 0;
    float hmax = __fsub_rn(img_info[b * 3 + 0], 1.0f);
    float wmax = __fsub_rn(img_info[b * 3 + 1], 1.0f);

    // ---- prolog: decode segment 0
    if (t < SEG) {
        u64 key = cand[(size_t)b * CAP + t];
        float4 bx = decode_box(key, b, deltas, hmax, wmax);
        segBox[0][t] = bx;
        segArea[0][t] = box_area(bx);
    }
    __syncthreads();
    // tile for seg 0 (waves 0..9) + pack aliveW[0] (all rows valid)
    if (w < 10) {
        int u = NE_UNITS[w];
        int wc = u & 3, h = u >> 2;
        int c = wc * 64 + lane;
        float4 cb = segBox[0][c];
        float  ca = segArea[0][c];
        for (int r = h * 64; r < h * 64 + 64; ++r) {
            float4 rb = segBox[0][r];
            float  ra = segArea[0][r];
            bool bit = (r < c) && iou_supp(rb, ra, cb, ca);
            u64 bal = __ballot(bit);
            if (lane == 0) tile[0][r][2 * wc]     = (u32)bal;
            if (lane == 1) tile[0][r][2 * wc + 1] = (u32)(bal >> 32);
        }
    }
    if (t < SEG) {
        u64 bal = __ballot(true);
        if (lane == 0) aliveW[0][2 * w]     = (u32)bal;
        if (lane == 1) aliveW[0][2 * w + 1] = (u32)(bal >> 32);
    }

    int Kprev = 0;
    for (int s = 0; s < NSEG; ++s) {
        int bufc = s & 1, bufn = bufc ^ 1;
        __syncthreads();                       // barrier A
        int Kcur = Kvar;
        if (Kcur >= POST) break;               // uniform

        // ---- merged region (waves 0-3): phase3(seg s) + decode(seg s+1)
        if (t < SEG) {
            if (s > 0) {
                bool al = aliveB[bufc][0][t] && aliveB[bufc][1][t] && aliveB[bufc][2][t];
                if (al && Kcur > Kprev) {
                    float4 rb = segBox[bufc][t];
                    float  ra = segArea[bufc][t];
                    int k = Kprev;
                    while (k < Kcur) {
                        bool d0 = iou_supp(keptBox[k], keptArea[k], rb, ra);
                        bool d1 = ((k + 1) < Kcur) & iou_supp(keptBox[k + 1], keptArea[k + 1], rb, ra);
                        bool d2 = ((k + 2) < Kcur) & iou_supp(keptBox[k + 2], keptArea[k + 2], rb, ra);
                        bool d3 = ((k + 3) < Kcur) & iou_supp(keptBox[k + 3], keptArea[k + 3], rb, ra);
                        if (d0 | d1 | d2 | d3) { al = false; break; }
                        k += 4;
                    }
                }
                u64 bal = __ballot(al);
                if (lane == 0) aliveW[bufc][2 * w]     = (u32)bal;
                if (lane == 1) aliveW[bufc][2 * w + 1] = (u32)(bal >> 32);
            }
            if (s + 1 < NSEG) {
                int g = (s + 1) * SEG + t;
                float4 bx = make_float4(0.f, 0.f, 0.f, 0.f);
                float ar = 0.f;
                bool valid = (g < PRE);
                if (valid) {
                    u64 key = cand[(size_t)b * CAP + g];
                    bx = decode_box(key, b, deltas, hmax, wmax);
                    ar = box_area(bx);
                }
                segBox[bufn][t] = bx;
                segArea[bufn][t] = ar;
                unsigned char v8 = valid ? 1 : 0;
                aliveB[bufn][0][t] = v8; aliveB[bufn][1][t] = v8; aliveB[bufn][2][t] = v8;
            }
        }
        __syncthreads();                       // barrier B

        if (w == 0) {
            // ---- serial greedy scan of segment s (wave 0)
            int l = lane;
            u32 va = (l < 8) ? aliveW[bufc][l] : 0u;
            int KK = Kcur;
            while (true) {
                u64 balv = __ballot(va != 0u);
                if (balv == 0ULL) break;
                int wsel = __ffsll(balv) - 1;
                u32 word = __builtin_amdgcn_readlane(va, wsel);
                int r = (wsel << 5) + (__ffs(word) - 1);
                u32 trow = tile[bufc][r][l & 7];
                if (l >= 8 && l < 12)
                    ((float*)keptBox)[KK * 4 + (l - 8)] = ((const float*)segBox[bufc])[r * 4 + (l - 8)];
                if (l == 12) keptArea[KK] = segArea[bufc][r];
                u32 self = (l == (r >> 5)) ? (1u << (r & 31)) : 0u;
                if (l < 8) va &= ~(trow | self);
                ++KK;
                if (KK == POST) break;
            }
            if (l == 0) Kvar = KK;
        } else if (w <= 12) {
            // ---- phase A for segment s+1 (waves 1-12): wave-uniform k
            if (s + 1 < NSEG && Kcur > 0) {
                int rg = (w - 1) & 3;
                int kc = (w - 1) >> 2;          // 0..2
                int row = rg * 64 + lane;
                float4 rb = segBox[bufn][row];
                float  ra = segArea[bufn][row];
                bool dead = false, written = false;
                int k = kc;
                int q = 0;
                while (k < Kcur) {
                    int k1 = k + 3, k2 = k + 6, k3 = k + 9;
                    bool d0 = iou_supp(keptBox[k], keptArea[k], rb, ra);
                    bool d1 = (k1 < Kcur) & iou_supp(keptBox[k1], keptArea[k1], rb, ra);
                    bool d2 = (k2 < Kcur) & iou_supp(keptBox[k2], keptArea[k2], rb, ra);
                    bool d3 = (k3 < Kcur) & iou_supp(keptBox[k3], keptArea[k3], rb, ra);
                    dead |= (d0 | d1 | d2 | d3);
                    k += 12;
                    if (((++q) & 7) == 0) {
                        if (dead && !written) { aliveB[bufn][kc][row] = 0; written = true; }
                        u32 comb = (u32)aliveB[bufn][0][row] & (u32)aliveB[bufn][1][row] &
                                   (u32)aliveB[bufn][2][row];
                        if (__ballot(comb != 0u) == 0ULL) break;
                    }
                }
                if (dead && !written) aliveB[bufn][kc][row] = 0;
            }
        } else {
            // ---- intra-segment tile build for s+1 (waves 13-15)
            if (s + 1 < NSEG) {
                int g3 = w - 13;
                int nu = TILE_N[g3];
                for (int ui = 0; ui < nu; ++ui) {
                    int u = TILE_U[g3][ui];
                    int wc = u & 3, h = u >> 2;
                    int c = wc * 64 + lane;
                    float4 cb = segBox[bufn][c];
                    float  ca = segArea[bufn][c];
                    for (int r = h * 64; r < h * 64 + 64; ++r) {
                        float4 rb = segBox[bufn][r];
                        float  ra = segArea[bufn][r];
                        bool bit = (r < c) && iou_supp(rb, ra, cb, ca);
                        u64 bal = __ballot(bit);
                        if (lane == 0) tile[bufn][r][2 * wc]     = (u32)bal;
                        if (lane == 1) tile[bufn][r][2 * wc + 1] = (u32)(bal >> 32);
                    }
                }
            }
        }
        Kprev = Kcur;
    }
    __syncthreads();

    // ---- epilogue: write output
    int K = Kvar;
    for (int s2 = t; s2 < POST; s2 += 1024) {
        float* o = out + ((size_t)b * POST + s2) * 5;
        if (s2 < K) {
            float4 bx = keptBox[s2];
            o[0] = (float)b; o[1] = bx.x; o[2] = bx.y; o[3] = bx.z; o[4] = bx.w;
        } else {
            o[0] = (float)b; o[1] = 0.f; o[2] = 0.f; o[3] = 0.f; o[4] = 0.f;
        }
    }
}

// ---------------- fallback: monolithic sort+decode+NMS (small ws) --------------
__global__ __launch_bounds__(1024) void final_kernel(const u64* __restrict__ cand, const u32* __restrict__ cntp,
                             const float* __restrict__ deltas, const float* __restrict__ img_info,
                             float* __restrict__ out) {
    __shared__ union {
        u64 keys[CAP];
        struct {
            float boxes[PRE][4];
            float areas[PRE];
            u32   alive[192];
        } n;
    } sh;
    __shared__ int s_next;

    int b = blockIdx.x;
    int tid = threadIdx.x;

    for (int s = tid; s < POST; s += 1024) {
        float* o = out + ((size_t)b * POST + s) * 5;
        o[0] = (float)b; o[1] = 0.f; o[2] = 0.f; o[3] = 0.f; o[4] = 0.f;
    }

    int n = (int)min(cntp[b * 64], (u32)CAP);
    for (int i = tid; i < CAP; i += 1024)
        sh.keys[i] = (i < n) ? cand[(size_t)b * CAP + i] : 0ULL;
    __syncthreads();

    for (int k = 2; k <= CAP; k <<= 1) {
        for (int j = k >> 1; j > 0; j >>= 1) {
            for (int i = tid; i < CAP; i += 1024) {
                int ixj = i ^ j;
                if (ixj > i) {
                    u64 x = sh.keys[i], y = sh.keys[ixj];
                    bool desc = ((i & k) == 0);
                    if (desc ? (x < y) : (x > y)) { sh.keys[i] = y; sh.keys[ixj] = x; }
                }
            }
            __syncthreads();
        }
    }

    u32 myIdx[6];
    #pragma unroll
    for (int r = 0; r < 6; r++) {
        int i = tid + r * 1024;
        if (i < PRE) myIdx[r] = ~(u32)(sh.keys[i]);
    }
    __syncthreads();

    float hmax = __fsub_rn(img_info[b * 3 + 0], 1.0f);
    float wmax = __fsub_rn(img_info[b * 3 + 1], 1.0f);

    #pragma unroll
    for (int r = 0; r < 6; r++) {
        int i = tid + r * 1024;
        if (i < PRE) {
            int a = (int)myIdx[r];
            float a0, a1, a2, a3;
            anchor_at(a, a0, a1, a2, a3);
            const float4 d4 = *(const float4*)(deltas + ((size_t)b * NA + a) * 4);
            float w  = __fadd_rn(__fsub_rn(a2, a0), 1.0f);
            float h  = __fadd_rn(__fsub_rn(a3, a1), 1.0f);
            float cx = __fadd_rn(a0, __fmul_rn(0.5f, w));
            float cy = __fadd_rn(a1, __fmul_rn(0.5f, h));
            float pcx = __fadd_rn(__fmul_rn(d4.x, w), cx);
            float pcy = __fadd_rn(__fmul_rn(d4.y, h), cy);
            float pw  = __fmul_rn((float)exp((double)d4.z), w);
            float ph  = __fmul_rn((float)exp((double)d4.w), h);
            float x1 = __fsub_rn(pcx, __fmul_rn(0.5f, pw));
            float y1 = __fsub_rn(pcy, __fmul_rn(0.5f, ph));
            float x2 = __fadd_rn(pcx, __fmul_rn(0.5f, pw));
            float y2 = __fadd_rn(pcy, __fmul_rn(0.5f, ph));
            x1 = fminf(fmaxf(x1, 0.f), wmax);
            x2 = fminf(fmaxf(x2, 0.f), wmax);
            y1 = fminf(fmaxf(y1, 0.f), hmax);
            y2 = fminf(fmaxf(y2, 0.f), hmax);
            sh.n.boxes[i][0] = x1; sh.n.boxes[i][1] = y1;
            sh.n.boxes[i][2] = x2; sh.n.boxes[i][3] = y2;
            sh.n.areas[i] = __fmul_rn(__fadd_rn(__fsub_rn(x2, x1), 1.0f),
                                      __fadd_rn(__fsub_rn(y2, y1), 1.0f));
        }
    }

    for (int wdi = tid; wdi < 192; wdi += 1024) {
        u32 v = 0xFFFFFFFFu;
        if (wdi == 187) v = 0x0000FFFFu;
        if (wdi > 187)  v = 0u;
        sh.n.alive[wdi] = v;
    }
    __syncthreads();

    int kept = 0;
    int scanWord = 0;
    while (kept < POST) {
        if (tid == 0) {
            int found = -1;
            while (scanWord < 188) {
                u32 wv = sh.n.alive[scanWord];
                if (wv) { found = scanWord * 32 + (__ffs(wv) - 1); break; }
                scanWord++;
            }
            s_next = found;
        }
        __syncthreads();
        int i = s_next;
        if (i < 0) break;
        float bx1 = sh.n.boxes[i][0], by1 = sh.n.boxes[i][1];
        float bx2 = sh.n.boxes[i][2], by2 = sh.n.boxes[i][3];
        float bar = sh.n.areas[i];
        if (tid == 0) {
            float* o = out + ((size_t)b * POST + kept) * 5;
            o[1] = bx1; o[2] = by1; o[3] = bx2; o[4] = by2;
            atomicAnd(&sh.n.alive[i >> 5], ~(1u << (i & 31)));
        }
        for (int j = i + 1 + tid; j < PRE; j += 1024) {
            float x1 = sh.n.boxes[j][0], y1 = sh.n.boxes[j][1];
            float x2 = sh.n.boxes[j][2], y2 = sh.n.boxes[j][3];
            float xx1 = fmaxf(x1, bx1), yy1 = fmaxf(y1, by1);
            float xx2 = fminf(x2, bx2), yy2 = fminf(y2, by2);
            float iw = fmaxf(__fadd_rn(__fsub_rn(xx2, xx1), 1.0f), 0.f);
            float ih = fmaxf(__fadd_rn(__fsub_rn(yy2, yy1), 1.0f), 0.f);
            float inter = __fmul_rn(iw, ih);
            float denom = __fsub_rn(__fadd_rn(sh.n.areas[j], bar), inter);
            float iou = __fdiv_rn(inter, denom);
            if (iou > 0.7f) atomicAnd(&sh.n.alive[j >> 5], ~(1u << (j & 31)));
        }
        kept++;
        __syncthreads();
    }
}

// ---------------- launcher -----------------------------------------------------
extern "C" void kernel_launch(void* const* d_in, const int* in_sizes, int n_in,
                              void* d_out, int out_size, void* d_ws, size_t ws_size,
                              hipStream_t stream) {
    const float* probs    = (const float*)d_in[0];
    const float* deltas   = (const float*)d_in[1];
    const float* img_info = (const float*)d_in[2];
    float* out = (float*)d_out;

    char* ws = (char*)d_ws;
    size_t off = 0;
    u32* cntp = (u32*)(ws + off); off += (size_t)NB * 64 * sizeof(u32);      // 4 KiB
    u32* flag = (u32*)(ws + off); off += (size_t)NB * 64 * sizeof(u32);      // 4 KiB
    u32* thr  = (u32*)(ws + off); off += 4096;
    u32* hist = (u32*)(ws + off); off += (size_t)NB * 65536 * sizeof(u32);   // 4 MiB
    u64* cand = (u64*)(ws + off); off += (size_t)NB * CAP * sizeof(u64);     // 1 MiB
    bool bigws = (ws_size >= off);

    dim3 gA((NA + 255) / 256, NB);

    hipMemsetAsync(cntp, 0, (size_t)NB * 64 * sizeof(u32), stream);

    if (bigws) {
        compact_fixed<<<gA, 256, 0, stream>>>(probs, cntp, cand);
        check_kernel<<<1, 64, 0, stream>>>(cntp, flag);
        // gated exact fallback (no-ops when all flags clean)
        zero_hist<<<dim3(256, NB), 256, 0, stream>>>(flag, hist);
        hist_kernel<<<gA, 256, 0, stream>>>(flag, probs, hist);
        thresh_kernel<<<NB, 1024, 0, stream>>>(flag, hist, thr);
        compact2_kernel<<<gA, 256, 0, stream>>>(flag, probs, thr, cntp, cand);
        // main pipeline
        sort_kernel<<<NB, 1024, 0, stream>>>(cand, cntp);
        nms_fused<<<NB, 1024, 0, stream>>>(cand, deltas, img_info, out);
    } else {
        hipMemsetAsync(flag, 1, (size_t)NB * 64 * sizeof(u32), stream);
        hipMemsetAsync(hist, 0, (size_t)NB * 65536 * sizeof(u32), stream);
        hist_kernel<<<gA, 256, 0, stream>>>(flag, probs, hist);
        thresh_kernel<<<NB, 1024, 0, stream>>>(flag, hist, thr);
        compact2_kernel<<<gA, 256, 0, stream>>>(flag, probs, thr, cntp, cand);
        final_kernel<<<NB, 1024, 0, stream>>>(cand, cntp, deltas, img_info, out);
    }
}

// Round 10
// 494.449 us; speedup vs baseline: 1.2862x; 1.0468x over previous
//
#include <hip/hip_runtime.h>

#define NB 16
#define NA 261888
#define PRE 6000
#define POST 1000
#define CAP 8192
#define SEG 256
#define NSEG ((PRE + SEG - 1) / SEG)   // 24
#define KPAD 1024
#define THRF 0.972f
// Exact NMS predicate: RN32(inter/denom) > 0.7f  <=>  inter >= M*denom with
// M = midpoint(0.7f, nextafterf) = 0x1.666667p-1 (25-bit mantissa).
// f32-only form: fmaf(0.7f, denom, -inter) <= -2^-25*denom. Exact because
// M*denom - inter lies on a lattice of spacing 2^(ed-48) while the RN hazard
// band around -T is 2^(ed-49); equality (e==-T) included on both sides.
#define MBOUND 0x1.666667p-1

typedef unsigned int u32;
typedef unsigned long long u64;

__device__ __constant__ int NE_UNITS[10] = {0, 1, 2, 3, 5, 6, 7, 10, 11, 15};

__device__ inline float box_area(float4 v) {
    return __fmul_rn(__fadd_rn(__fsub_rn(v.z, v.x), 1.0f),
                     __fadd_rn(__fsub_rn(v.w, v.y), 1.0f));
}

__device__ inline bool iou_supp(float4 a, float aa, float4 c, float ca) {
    float xx1 = fmaxf(c.x, a.x);
    float yy1 = fmaxf(c.y, a.y);
    float xx2 = fminf(c.z, a.z);
    float yy2 = fminf(c.w, a.w);
    float iw = fmaxf(__fadd_rn(__fsub_rn(xx2, xx1), 1.0f), 0.f);
    float ih = fmaxf(__fadd_rn(__fsub_rn(yy2, yy1), 1.0f), 0.f);
    float inter = __fmul_rn(iw, ih);
    float denom = __fsub_rn(__fadd_rn(ca, aa), inter);
    // exact f32 predicate (see header comment)
    return __fmaf_rn(0.7f, denom, -inter) <= __fmul_rn(denom, -0x1p-25f);
}

// ---------------- anchors (match numpy float64 -> float32 exactly) -------------
__device__ inline void anchor_at(int idx, float& a0, float& a1, float& a2, float& a3) {
    int base, fw, stride, scale;
    if (idx < 196608)      { base = 0;      fw = 256; stride = 4;  scale = 4; }
    else if (idx < 245760) { base = 196608; fw = 128; stride = 8;  scale = 8; }
    else if (idx < 258048) { base = 245760; fw = 64;  stride = 16; scale = 16; }
    else if (idx < 261120) { base = 258048; fw = 32;  stride = 32; scale = 32; }
    else                   { base = 261120; fw = 16;  stride = 64; scale = 64; }
    int rel  = idx - base;
    int ri   = rel % 3;
    int cell = rel / 3;
    int col  = cell & (fw - 1);
    int row  = cell / fw;
    double cx = (col + 0.5) * (double)stride;
    double cy = (row + 0.5) * (double)stride;
    double sz = (double)scale * 8.0;
    double sq = (ri == 0) ? 0.7071067811865476 : ((ri == 1) ? 1.0 : 1.4142135623730951);
    double wsd = sz * sq;
    double hsd = sz / sq;
    a0 = (float)(cx - 0.5 * wsd);
    a1 = (float)(cy - 0.5 * hsd);
    a2 = (float)(cx + 0.5 * wsd);
    a3 = (float)(cy + 0.5 * hsd);
}

__device__ inline float4 decode_box(u64 key, int b, const float* __restrict__ deltas,
                                    float hmax, float wmax) {
    int a = (int)(~(u32)key);
    float a0, a1, a2, a3;
    anchor_at(a, a0, a1, a2, a3);
    const float4 d4 = *(const float4*)(deltas + ((size_t)b * NA + a) * 4);
    float w  = __fadd_rn(__fsub_rn(a2, a0), 1.0f);
    float h  = __fadd_rn(__fsub_rn(a3, a1), 1.0f);
    float cx = __fadd_rn(a0, __fmul_rn(0.5f, w));
    float cy = __fadd_rn(a1, __fmul_rn(0.5f, h));
    float pcx = __fadd_rn(__fmul_rn(d4.x, w), cx);
    float pcy = __fadd_rn(__fmul_rn(d4.y, h), cy);
    float pw  = __fmul_rn((float)exp((double)d4.z), w);
    float ph  = __fmul_rn((float)exp((double)d4.w), h);
    float x1 = __fsub_rn(pcx, __fmul_rn(0.5f, pw));
    float y1 = __fsub_rn(pcy, __fmul_rn(0.5f, ph));
    float x2 = __fadd_rn(pcx, __fmul_rn(0.5f, pw));
    float y2 = __fadd_rn(pcy, __fmul_rn(0.5f, ph));
    x1 = fminf(fmaxf(x1, 0.f), wmax);
    x2 = fminf(fmaxf(x2, 0.f), wmax);
    y1 = fminf(fmaxf(y1, 0.f), hmax);
    y2 = fminf(fmaxf(y2, 0.f), hmax);
    return make_float4(x1, y1, x2, y2);
}

// ---------------- fast path: fixed-threshold compact, block-aggregated ---------
__global__ void compact_fixed(const float* __restrict__ probs, u32* __restrict__ cntp,
                              u64* __restrict__ cand) {
    __shared__ u32 lcnt;
    __shared__ u32 lbase;
    int tid = threadIdx.x;
    int a = blockIdx.x * 256 + tid;
    int b = blockIdx.y;
    if (tid == 0) lcnt = 0;
    __syncthreads();
    float2 pv = *(const float2*)(probs + ((size_t)b * NA + a) * 2);
    float s = pv.y;
    u32 bits = __float_as_uint(s);
    int lpos = -1;
    if (s >= THRF) lpos = (int)atomicAdd(&lcnt, 1u);
    __syncthreads();
    if (tid == 0) lbase = lcnt ? atomicAdd(&cntp[b * 64], lcnt) : 0u;
    __syncthreads();
    if (lpos >= 0) {
        u32 pos = lbase + (u32)lpos;
        if (pos < CAP)
            cand[(size_t)b * CAP + pos] = ((u64)bits << 32) | (u32)(~(u32)a);
    }
}

// ---------------- validate fast path; set per-batch fallback flags -------------
__global__ void check_kernel(u32* __restrict__ cntp, u32* __restrict__ flag) {
    int t = threadIdx.x;
    if (t < NB) {
        u32 c = cntp[t * 64];
        u32 bad = (c < (u32)PRE || c > (u32)CAP) ? 1u : 0u;
        flag[t * 64] = bad;
        if (bad) cntp[t * 64] = 0;
    }
}

// ---------------- gated fallback: zero hist ------------------------------------
__global__ void zero_hist(const u32* __restrict__ flag, u32* __restrict__ hist) {
    int b = blockIdx.y;
    if (flag[b * 64] == 0) return;
    int i = blockIdx.x * 256 + threadIdx.x;
    hist[(size_t)b * 65536 + i] = 0;
}

// ---------------- gated fallback: histogram ------------------------------------
__global__ void hist_kernel(const u32* __restrict__ flag, const float* __restrict__ probs,
                            u32* __restrict__ hist) {
    int b = blockIdx.y;
    if (flag[b * 64] == 0) return;
    int a = blockIdx.x * 256 + threadIdx.x;
    float2 pv = *(const float2*)(probs + ((size_t)b * NA + a) * 2);
    u32 bits = __float_as_uint(pv.y);
    atomicAdd(&hist[(size_t)b * 65536 + (bits >> 16)], 1u);
}

// ---------------- gated fallback: per-batch threshold --------------------------
__global__ __launch_bounds__(1024) void thresh_kernel(const u32* __restrict__ flag,
                                                      const u32* __restrict__ hist,
                                                      u32* __restrict__ thr) {
    int b = blockIdx.x;
    if (flag[b * 64] == 0) return;
    __shared__ u32 csum[1024];
    int t = threadIdx.x;
    const u32* h = hist + (size_t)b * 65536;
    u32 s = 0;
    for (int k = 0; k < 64; k++) s += h[t * 64 + k];
    csum[t] = s;
    __syncthreads();
    if (t == 0) {
        u32 cum = 0;
        int bucket = 0;
        for (int c = 1023; c >= 0; c--) {
            if (cum + csum[c] >= (u32)PRE) {
                u32 cum2 = cum;
                for (int k = 63; k >= 0; k--) {
                    cum2 += h[c * 64 + k];
                    if (cum2 >= (u32)PRE) { bucket = c * 64 + k; break; }
                }
                break;
            }
            cum += csum[c];
        }
        thr[b] = (u32)bucket << 16;
    }
}

// ---------------- gated fallback: compact with exact threshold -----------------
__global__ void compact2_kernel(const u32* __restrict__ flag, const float* __restrict__ probs,
                                const u32* __restrict__ thr, u32* __restrict__ cntp,
                                u64* __restrict__ cand) {
    int b = blockIdx.y;
    if (flag[b * 64] == 0) return;
    __shared__ u32 lcnt;
    __shared__ u32 lbase;
    int tid = threadIdx.x;
    int a = blockIdx.x * 256 + tid;
    if (tid == 0) lcnt = 0;
    __syncthreads();
    float2 pv = *(const float2*)(probs + ((size_t)b * NA + a) * 2);
    u32 bits = __float_as_uint(pv.y);
    int lpos = -1;
    if (bits >= thr[b]) lpos = (int)atomicAdd(&lcnt, 1u);
    __syncthreads();
    if (tid == 0) lbase = lcnt ? atomicAdd(&cntp[b * 64], lcnt) : 0u;
    __syncthreads();
    if (lpos >= 0) {
        u32 pos = lbase + (u32)lpos;
        if (pos < CAP)
            cand[(size_t)b * CAP + pos] = ((u64)bits << 32) | (u32)(~(u32)a);
    }
}

// ---------------- per-batch bitonic sort of candidate keys ---------------------
__global__ __launch_bounds__(1024) void sort_kernel(u64* __restrict__ cand, const u32* __restrict__ cntp) {
    __shared__ u64 keys[CAP];
    int b = blockIdx.x, tid = threadIdx.x;
    int n = (int)min(cntp[b * 64], (u32)CAP);
    u64* cb = cand + (size_t)b * CAP;
    for (int i = tid; i < CAP; i += 1024) keys[i] = (i < n) ? cb[i] : 0ULL;
    __syncthreads();
    for (int k = 2; k <= CAP; k <<= 1) {
        for (int j = k >> 1; j > 0; j >>= 1) {
            for (int i = tid; i < CAP; i += 1024) {
                int ixj = i ^ j;
                if (ixj > i) {
                    u64 x = keys[i], y = keys[ixj];
                    bool desc = ((i & k) == 0);
                    if (desc ? (x < y) : (x > y)) { keys[i] = y; keys[ixj] = x; }
                }
            }
            __syncthreads();
        }
    }
    for (int i = tid; i < PRE; i += 1024) cb[i] = keys[i];
}

// ---------------- pipelined fused lazy NMS (spatially binned phase A) ----------
// One block/batch, 1024 threads, double-buffered 256-row segments.
// Merged region (5 barriers): phase3(bufc)+decode(bufn)+Morton-bin counting
// sort of bufn rows -> perm[]. Concurrent region: wave0 serial scan of bufc;
// waves 1-15 phase A of bufn on SORTED rows with wave-bbox rect rejects
// (wave-uniform -> execz skip of the IoU); waves 1-10 then build the
// strict-upper intra-segment bit tile.
__global__ __launch_bounds__(1024) void nms_fused(const u64* __restrict__ cand,
                                                  const float* __restrict__ deltas,
                                                  const float* __restrict__ img_info,
                                                  float* __restrict__ out) {
    __shared__ float4 segBox[2][SEG];
    __shared__ float  segArea[2][SEG];
    __shared__ u32    tile[2][SEG][8];
    __shared__ u32    aliveW[2][8];
    __shared__ unsigned char aliveB[4][SEG];
    __shared__ float4 keptBox[KPAD];
    __shared__ float  keptArea[KPAD];
    __shared__ unsigned char keyB[SEG];
    __shared__ short  rankB[SEG];
    __shared__ short  perm[SEG];
    __shared__ u32    binCnt[64];
    __shared__ u32    binOff[64];
    __shared__ int    Kvar;

    int b = blockIdx.x;
    int t = threadIdx.x;
    int lane = t & 63;
    int w = t >> 6;
    if (t == 0) Kvar = 0;
    float hmax = __fsub_rn(img_info[b * 3 + 0], 1.0f);
    float wmax = __fsub_rn(img_info[b * 3 + 1], 1.0f);

    // ---- prolog: decode segment 0 + its tile + aliveW
    if (t < SEG) {
        u64 key = cand[(size_t)b * CAP + t];
        float4 bx = decode_box(key, b, deltas, hmax, wmax);
        segBox[0][t] = bx;
        segArea[0][t] = box_area(bx);
    }
    __syncthreads();
    if (w < 10) {
        int u = NE_UNITS[w];
        int wc = u & 3, h = u >> 2;
        int c = wc * 64 + lane;
        float4 cb = segBox[0][c];
        float  ca = segArea[0][c];
        for (int r = h * 64; r < h * 64 + 64; ++r) {
            float4 rb = segBox[0][r];
            float  ra = segArea[0][r];
            bool bit = (r < c) && iou_supp(rb, ra, cb, ca);
            u64 bal = __ballot(bit);
            if (lane == 0) tile[0][r][2 * wc]     = (u32)bal;
            if (lane == 1) tile[0][r][2 * wc + 1] = (u32)(bal >> 32);
        }
    }
    if (t < SEG) {
        u64 bal = __ballot(true);
        if (lane == 0) aliveW[0][2 * w]     = (u32)bal;
        if (lane == 1) aliveW[0][2 * w + 1] = (u32)(bal >> 32);
    }

    int Kprev = 0;
    for (int s = 0; s < NSEG; ++s) {
        int bufc = s & 1, bufn = bufc ^ 1;
        __syncthreads();                       // barrier A
        int Kcur = Kvar;
        if (Kcur >= POST) break;               // uniform

        // ---- R1: phase3(bufc) + decode(bufn) + key; wave15 zeroes binCnt
        if (t < SEG) {
            if (s > 0) {
                bool al = aliveB[0][t] && aliveB[1][t] && aliveB[2][t] && aliveB[3][t];
                if (al && Kcur > Kprev) {
                    float4 rb = segBox[bufc][t];
                    float  ra = segArea[bufc][t];
                    int k = Kprev;
                    while (k < Kcur) {
                        bool d0 = iou_supp(keptBox[k], keptArea[k], rb, ra);
                        bool d1 = ((k + 1) < Kcur) & iou_supp(keptBox[k + 1], keptArea[k + 1], rb, ra);
                        bool d2 = ((k + 2) < Kcur) & iou_supp(keptBox[k + 2], keptArea[k + 2], rb, ra);
                        bool d3 = ((k + 3) < Kcur) & iou_supp(keptBox[k + 3], keptArea[k + 3], rb, ra);
                        if (d0 | d1 | d2 | d3) { al = false; break; }
                        k += 4;
                    }
                }
                u64 bal = __ballot(al);
                if (lane == 0) aliveW[bufc][2 * w]     = (u32)bal;
                if (lane == 1) aliveW[bufc][2 * w + 1] = (u32)(bal >> 32);
            }
            if (s + 1 < NSEG) {
                int g = (s + 1) * SEG + t;
                float4 bx = make_float4(0.f, 0.f, 0.f, 0.f);
                float ar = 0.f;
                bool valid = (g < PRE);
                if (valid) {
                    u64 key = cand[(size_t)b * CAP + g];
                    bx = decode_box(key, b, deltas, hmax, wmax);
                    ar = box_area(bx);
                }
                segBox[bufn][t] = bx;
                segArea[bufn][t] = ar;
                unsigned char v8 = valid ? 1 : 0;
                aliveB[0][t] = v8; aliveB[1][t] = v8; aliveB[2][t] = v8; aliveB[3][t] = v8;
                int bxq = (int)bx.x >> 7; bxq = (bxq < 0) ? 0 : ((bxq > 7) ? 7 : bxq);
                int byq = (int)bx.y >> 7; byq = (byq < 0) ? 0 : ((byq > 7) ? 7 : byq);
                int key6 = (bxq & 1) | ((byq & 1) << 1) | ((bxq & 2) << 1) |
                           ((byq & 2) << 2) | ((bxq & 4) << 2) | ((byq & 4) << 3);
                keyB[t] = (unsigned char)key6;
            }
        } else if (t >= 960) {
            int i = t - 960;
            binCnt[i] = 0;
        }
        __syncthreads();                       // barrier A2
        if (t < SEG && s + 1 < NSEG)
            rankB[t] = (short)atomicAdd(&binCnt[keyB[t]], 1u);
        __syncthreads();                       // barrier A3
        if (t < 64) {
            u32 c = binCnt[t];
            u32 x = c;
            for (int off = 1; off < 64; off <<= 1) {
                u32 y = __shfl_up(x, off);
                if (lane >= off) x += y;
            }
            binOff[t] = x - c;
        }
        __syncthreads();                       // barrier A4
        if (t < SEG && s + 1 < NSEG)
            perm[binOff[keyB[t]] + rankB[t]] = (short)t;
        __syncthreads();                       // barrier B

        if (w == 0) {
            // ---- serial greedy scan of segment s (wave 0)
            int l = lane;
            u32 va = (l < 8) ? aliveW[bufc][l] : 0u;
            int KK = Kcur;
            while (true) {
                u64 balv = __ballot(va != 0u);
                if (balv == 0ULL) break;
                int wsel = __ffsll(balv) - 1;
                u32 word = __builtin_amdgcn_readlane(va, wsel);
                int r = (wsel << 5) + (__ffs(word) - 1);
                u32 trow = tile[bufc][r][l & 7];
                if (l >= 8 && l < 12)
                    ((float*)keptBox)[KK * 4 + (l - 8)] = ((const float*)segBox[bufc])[r * 4 + (l - 8)];
                if (l == 12) keptArea[KK] = segArea[bufc][r];
                u32 self = (l == (r >> 5)) ? (1u << (r & 31)) : 0u;
                if (l < 8) va &= ~(trow | self);
                ++KK;
                if (KK == POST) break;
            }
            if (l == 0) Kvar = KK;
        } else {
            int ww = w - 1;                    // 0..14
            if (s + 1 < NSEG && Kcur > 0) {
                // ---- phase A on sorted rows with wave-bbox rejects
                int rg, kc, kstep;
                if (ww < 12) { rg = ww >> 2; kc = ww & 3; kstep = 4; }
                else         { rg = 3;       kc = ww - 12; kstep = 3; }
                int row = (int)perm[rg * 64 + lane];
                float4 rb = segBox[bufn][row];
                float  ra = segArea[bufn][row];
                float bx1 = rb.x, by1 = rb.y, bx2 = rb.z, by2 = rb.w;
                for (int off = 32; off; off >>= 1) {
                    bx1 = fminf(bx1, __shfl_xor(bx1, off));
                    by1 = fminf(by1, __shfl_xor(by1, off));
                    bx2 = fmaxf(bx2, __shfl_xor(bx2, off));
                    by2 = fmaxf(by2, __shfl_xor(by2, off));
                }
                bool dead = false, written = false;
                int q = 0;
                for (int k = kc; k < Kcur; k += kstep) {
                    float4 kb = keptBox[k];
                    bool rej = (__fadd_rn(kb.z, 1.f) <= bx1) | (__fadd_rn(bx2, 1.f) <= kb.x) |
                               (__fadd_rn(kb.w, 1.f) <= by1) | (__fadd_rn(by2, 1.f) <= kb.y);
                    if (!rej)
                        dead |= iou_supp(kb, keptArea[k], rb, ra);
                    if (((++q) & 15) == 0) {
                        if (dead && !written) { aliveB[kc][row] = 0; written = true; }
                        u32 comb = (u32)aliveB[0][row] & (u32)aliveB[1][row] &
                                   (u32)aliveB[2][row] & (u32)aliveB[3][row];
                        if (__ballot(comb != 0u) == 0ULL) break;
                    }
                }
                if (dead && !written) aliveB[kc][row] = 0;
            }
            // ---- intra-segment tile build for s+1 (waves 1..10, one unit each)
            if (s + 1 < NSEG && ww < 10) {
                int u = NE_UNITS[ww];
                int wc = u & 3, h = u >> 2;
                int c = wc * 64 + lane;
                float4 cb = segBox[bufn][c];
                float  ca = segArea[bufn][c];
                for (int r = h * 64; r < h * 64 + 64; ++r) {
                    float4 rb = segBox[bufn][r];
                    float  ra = segArea[bufn][r];
                    bool bit = (r < c) && iou_supp(rb, ra, cb, ca);
                    u64 bal = __ballot(bit);
                    if (lane == 0) tile[bufn][r][2 * wc]     = (u32)bal;
                    if (lane == 1) tile[bufn][r][2 * wc + 1] = (u32)(bal >> 32);
                }
            }
        }
        Kprev = Kcur;
    }
    __syncthreads();

    // ---- epilogue: write output
    int K = Kvar;
    for (int s2 = t; s2 < POST; s2 += 1024) {
        float* o = out + ((size_t)b * POST + s2) * 5;
        if (s2 < K) {
            float4 bx = keptBox[s2];
            o[0] = (float)b; o[1] = bx.x; o[2] = bx.y; o[3] = bx.z; o[4] = bx.w;
        } else {
            o[0] = (float)b; o[1] = 0.f; o[2] = 0.f; o[3] = 0.f; o[4] = 0.f;
        }
    }
}

// ---------------- fallback: monolithic sort+decode+NMS (small ws) --------------
__global__ __launch_bounds__(1024) void final_kernel(const u64* __restrict__ cand, const u32* __restrict__ cntp,
                             const float* __restrict__ deltas, const float* __restrict__ img_info,
                             float* __restrict__ out) {
    __shared__ union {
        u64 keys[CAP];
        struct {
            float boxes[PRE][4];
            float areas[PRE];
            u32   alive[192];
        } n;
    } sh;
    __shared__ int s_next;

    int b = blockIdx.x;
    int tid = threadIdx.x;

    for (int s = tid; s < POST; s += 1024) {
        float* o = out + ((size_t)b * POST + s) * 5;
        o[0] = (float)b; o[1] = 0.f; o[2] = 0.f; o[3] = 0.f; o[4] = 0.f;
    }

    int n = (int)min(cntp[b * 64], (u32)CAP);
    for (int i = tid; i < CAP; i += 1024)
        sh.keys[i] = (i < n) ? cand[(size_t)b * CAP + i] : 0ULL;
    __syncthreads();

    for (int k = 2; k <= CAP; k <<= 1) {
        for (int j = k >> 1; j > 0; j >>= 1) {
            for (int i = tid; i < CAP; i += 1024) {
                int ixj = i ^ j;
                if (ixj > i) {
                    u64 x = sh.keys[i], y = sh.keys[ixj];
                    bool desc = ((i & k) == 0);
                    if (desc ? (x < y) : (x > y)) { sh.keys[i] = y; sh.keys[ixj] = x; }
                }
            }
            __syncthreads();
        }
    }

    u32 myIdx[6];
    #pragma unroll
    for (int r = 0; r < 6; r++) {
        int i = tid + r * 1024;
        if (i < PRE) myIdx[r] = ~(u32)(sh.keys[i]);
    }
    __syncthreads();

    float hmax = __fsub_rn(img_info[b * 3 + 0], 1.0f);
    float wmax = __fsub_rn(img_info[b * 3 + 1], 1.0f);

    #pragma unroll
    for (int r = 0; r < 6; r++) {
        int i = tid + r * 1024;
        if (i < PRE) {
            int a = (int)myIdx[r];
            float a0, a1, a2, a3;
            anchor_at(a, a0, a1, a2, a3);
            const float4 d4 = *(const float4*)(deltas + ((size_t)b * NA + a) * 4);
            float w  = __fadd_rn(__fsub_rn(a2, a0), 1.0f);
            float h  = __fadd_rn(__fsub_rn(a3, a1), 1.0f);
            float cx = __fadd_rn(a0, __fmul_rn(0.5f, w));
            float cy = __fadd_rn(a1, __fmul_rn(0.5f, h));
            float pcx = __fadd_rn(__fmul_rn(d4.x, w), cx);
            float pcy = __fadd_rn(__fmul_rn(d4.y, h), cy);
            float pw  = __fmul_rn((float)exp((double)d4.z), w);
            float ph  = __fmul_rn((float)exp((double)d4.w), h);
            float x1 = __fsub_rn(pcx, __fmul_rn(0.5f, pw));
            float y1 = __fsub_rn(pcy, __fmul_rn(0.5f, ph));
            float x2 = __fadd_rn(pcx, __fmul_rn(0.5f, pw));
            float y2 = __fadd_rn(pcy, __fmul_rn(0.5f, ph));
            x1 = fminf(fmaxf(x1, 0.f), wmax);
            x2 = fminf(fmaxf(x2, 0.f), wmax);
            y1 = fminf(fmaxf(y1, 0.f), hmax);
            y2 = fminf(fmaxf(y2, 0.f), hmax);
            sh.n.boxes[i][0] = x1; sh.n.boxes[i][1] = y1;
            sh.n.boxes[i][2] = x2; sh.n.boxes[i][3] = y2;
            sh.n.areas[i] = __fmul_rn(__fadd_rn(__fsub_rn(x2, x1), 1.0f),
                                      __fadd_rn(__fsub_rn(y2, y1), 1.0f));
        }
    }

    for (int wdi = tid; wdi < 192; wdi += 1024) {
        u32 v = 0xFFFFFFFFu;
        if (wdi == 187) v = 0x0000FFFFu;
        if (wdi > 187)  v = 0u;
        sh.n.alive[wdi] = v;
    }
    __syncthreads();

    int kept = 0;
    int scanWord = 0;
    while (kept < POST) {
        if (tid == 0) {
            int found = -1;
            while (scanWord < 188) {
                u32 wv = sh.n.alive[scanWord];
                if (wv) { found = scanWord * 32 + (__ffs(wv) - 1); break; }
                scanWord++;
            }
            s_next = found;
        }
        __syncthreads();
        int i = s_next;
        if (i < 0) break;
        float bx1 = sh.n.boxes[i][0], by1 = sh.n.boxes[i][1];
        float bx2 = sh.n.boxes[i][2], by2 = sh.n.boxes[i][3];
        float bar = sh.n.areas[i];
        if (tid == 0) {
            float* o = out + ((size_t)b * POST + kept) * 5;
            o[1] = bx1; o[2] = by1; o[3] = bx2; o[4] = by2;
            atomicAnd(&sh.n.alive[i >> 5], ~(1u << (i & 31)));
        }
        for (int j = i + 1 + tid; j < PRE; j += 1024) {
            float x1 = sh.n.boxes[j][0], y1 = sh.n.boxes[j][1];
            float x2 = sh.n.boxes[j][2], y2 = sh.n.boxes[j][3];
            float xx1 = fmaxf(x1, bx1), yy1 = fmaxf(y1, by1);
            float xx2 = fminf(x2, bx2), yy2 = fminf(y2, by2);
            float iw = fmaxf(__fadd_rn(__fsub_rn(xx2, xx1), 1.0f), 0.f);
            float ih = fmaxf(__fadd_rn(__fsub_rn(yy2, yy1), 1.0f), 0.f);
            float inter = __fmul_rn(iw, ih);
            float denom = __fsub_rn(__fadd_rn(sh.n.areas[j], bar), inter);
            float iou = __fdiv_rn(inter, denom);
            if (iou > 0.7f) atomicAnd(&sh.n.alive[j >> 5], ~(1u << (j & 31)));
        }
        kept++;
        __syncthreads();
    }
}

// ---------------- launcher -----------------------------------------------------
extern "C" void kernel_launch(void* const* d_in, const int* in_sizes, int n_in,
                              void* d_out, int out_size, void* d_ws, size_t ws_size,
                              hipStream_t stream) {
    const float* probs    = (const float*)d_in[0];
    const float* deltas   = (const float*)d_in[1];
    const float* img_info = (const float*)d_in[2];
    float* out = (float*)d_out;

    char* ws = (char*)d_ws;
    size_t off = 0;
    u32* cntp = (u32*)(ws + off); off += (size_t)NB * 64 * sizeof(u32);
    u32* flag = (u32*)(ws + off); off += (size_t)NB * 64 * sizeof(u32);
    u32* thr  = (u32*)(ws + off); off += 4096;
    u32* hist = (u32*)(ws + off); off += (size_t)NB * 65536 * sizeof(u32);
    u64* cand = (u64*)(ws + off); off += (size_t)NB * CAP * sizeof(u64);
    bool bigws = (ws_size >= off);

    dim3 gA((NA + 255) / 256, NB);

    hipMemsetAsync(cntp, 0, (size_t)NB * 64 * sizeof(u32), stream);

    if (bigws) {
        compact_fixed<<<gA, 256, 0, stream>>>(probs, cntp, cand);
        check_kernel<<<1, 64, 0, stream>>>(cntp, flag);
        zero_hist<<<dim3(256, NB), 256, 0, stream>>>(flag, hist);
        hist_kernel<<<gA, 256, 0, stream>>>(flag, probs, hist);
        thresh_kernel<<<NB, 1024, 0, stream>>>(flag, hist, thr);
        compact2_kernel<<<gA, 256, 0, stream>>>(flag, probs, thr, cntp, cand);
        sort_kernel<<<NB, 1024, 0, stream>>>(cand, cntp);
        nms_fused<<<NB, 1024, 0, stream>>>(cand, deltas, img_info, out);
    } else {
        hipMemsetAsync(flag, 1, (size_t)NB * 64 * sizeof(u32), stream);
        hipMemsetAsync(hist, 0, (size_t)NB * 65536 * sizeof(u32), stream);
        hist_kernel<<<gA, 256, 0, stream>>>(flag, probs, hist);
        thresh_kernel<<<NB, 1024, 0, stream>>>(flag, hist, thr);
        compact2_kernel<<<gA, 256, 0, stream>>>(flag, probs, thr, cntp, cand);
        final_kernel<<<NB, 1024, 0, stream>>>(cand, cntp, deltas, img_info, out);
    }
}